// Round 1
// 1787.169 us; speedup vs baseline: 1.1054x; 1.1054x over previous
//
#include <hip/hip_runtime.h>
#include <math.h>

#define T_LEN 4096
#define DMODEL 2048
#define NH 16
#define CQKV 6144
#define CQKVZ 8192
#define SCALE 0.08838834764831845f   // 128^-0.5

using bf16x8 = __attribute__((ext_vector_type(8))) short;
using f32x4  = __attribute__((ext_vector_type(4))) float;

__device__ __forceinline__ float siluf(float x) { return x / (1.0f + __expf(-x)); }

__device__ __forceinline__ unsigned short f2bf(float f) {  // RNE
  unsigned int u = __float_as_uint(f);
  u = (u + 0x7FFFu + ((u >> 16) & 1u)) >> 16;
  return (unsigned short)u;
}
__device__ __forceinline__ float bf2f(unsigned short u) {
  return __uint_as_float(((unsigned int)u) << 16);
}
__device__ __forceinline__ ushort4 pack4(float a, float b, float c, float d) {
  ushort4 r; r.x = f2bf(a); r.y = f2bf(b); r.z = f2bf(c); r.w = f2bf(d); return r;
}

// ---------------- RMSNorm over D=2048; MODE: 1 = f32+bf16, 2 = bf16 only ----------------
template<int MODE>
__global__ __launch_bounds__(256) void rmsnorm_kernel(const float* __restrict__ x,
                                                      const float* __restrict__ w,
                                                      float* __restrict__ outf,
                                                      unsigned short* __restrict__ outb) {
  const int t = blockIdx.x;
  const int tid = threadIdx.x;
  const float4* xr = (const float4*)(x + (size_t)t * DMODEL);
  float4 v0 = xr[tid];
  float4 v1 = xr[tid + 256];
  float s = v0.x*v0.x + v0.y*v0.y + v0.z*v0.z + v0.w*v0.w
          + v1.x*v1.x + v1.y*v1.y + v1.z*v1.z + v1.w*v1.w;
#pragma unroll
  for (int off = 32; off > 0; off >>= 1) s += __shfl_down(s, off);
  __shared__ float red[4];
  if ((tid & 63) == 0) red[tid >> 6] = s;
  __syncthreads();
  const float tot = red[0] + red[1] + red[2] + red[3];
  const float r = rsqrtf(tot * (1.0f / DMODEL) + 1e-5f);
  const float4* wr = (const float4*)w;
  const float4 w0 = wr[tid], w1 = wr[tid + 256];
  float4 o0, o1;
  o0.x = v0.x*r*w0.x; o0.y = v0.y*r*w0.y; o0.z = v0.z*r*w0.z; o0.w = v0.w*r*w0.w;
  o1.x = v1.x*r*w1.x; o1.y = v1.y*r*w1.y; o1.z = v1.z*r*w1.z; o1.w = v1.w*r*w1.w;
  if (MODE == 1) {
    float4* orow = (float4*)(outf + (size_t)t * DMODEL);
    orow[tid] = o0;
    orow[tid + 256] = o1;
  }
  ushort4* brow = (ushort4*)(outb + (size_t)t * DMODEL);
  brow[tid] = pack4(o0.x, o0.y, o0.z, o0.w);
  brow[tid + 256] = pack4(o1.x, o1.y, o1.z, o1.w);
}

// ---------------- fp32 -> bf16 bulk convert ----------------
__global__ __launch_bounds__(256) void f2b_kernel(const float* __restrict__ in,
                                                  unsigned short* __restrict__ out) {
  const size_t i = (size_t)blockIdx.x * 256 + threadIdx.x;
  const float4 a = ((const float4*)in)[2 * i];
  const float4 b = ((const float4*)in)[2 * i + 1];
  ((ushort4*)out)[2 * i] = pack4(a.x, a.y, a.z, a.w);
  ((ushort4*)out)[2 * i + 1] = pack4(b.x, b.y, b.z, b.w);
}

// ---------------- bf16 MFMA GEMM: C[M][N] = A[M][K] * B[N][K]^T ----------------
// EPI: 0 = bf16 store, 1 = fp32 accumulate, 2 = silu(gate)*acc -> bf16 in place
template<int EPI>
__global__ __launch_bounds__(256) void gemm_bf16_kernel(const unsigned short* __restrict__ A,
                                                        const unsigned short* __restrict__ B,
                                                        float* __restrict__ Cf,
                                                        unsigned short* __restrict__ Cb,
                                                        int M, int N, int K) {
  __shared__ __align__(16) unsigned short As[128 * 40];
  __shared__ __align__(16) unsigned short Bs[128 * 40];
  const int bm = blockIdx.y * 128;
  const int bn = blockIdx.x * 128;
  const int tid = threadIdx.x;
  const int row = tid >> 1;
  const int co  = (tid & 1) * 16;
  const unsigned short* Ag = A + (size_t)(bm + row) * K + co;
  const unsigned short* Bg = B + (size_t)(bn + row) * K + co;
  unsigned short* Asw = &As[row * 40 + co];
  unsigned short* Bsw = &Bs[row * 40 + co];
  const int wv = tid >> 6;
  const int ln = tid & 63;
  const int mo = (wv >> 1) * 64;
  const int no = (wv & 1) * 64;
  const int fr = ln & 15;
  const int q8 = (ln >> 4) * 8;

  f32x4 acc[4][4];
  const f32x4 zero = {0.f, 0.f, 0.f, 0.f};
#pragma unroll
  for (int mi = 0; mi < 4; mi++)
#pragma unroll
    for (int ni = 0; ni < 4; ni++) acc[mi][ni] = zero;

  for (int k0 = 0; k0 < K; k0 += 32) {
    const uint4 av0 = *(const uint4*)(Ag + k0);
    const uint4 av1 = *(const uint4*)(Ag + k0 + 8);
    const uint4 bv0 = *(const uint4*)(Bg + k0);
    const uint4 bv1 = *(const uint4*)(Bg + k0 + 8);
    __syncthreads();
    *(uint4*)Asw = av0; *(uint4*)(Asw + 8) = av1;
    *(uint4*)Bsw = bv0; *(uint4*)(Bsw + 8) = bv1;
    __syncthreads();
    bf16x8 afr[4], bfr[4];
#pragma unroll
    for (int mi = 0; mi < 4; mi++)
      afr[mi] = *(const bf16x8*)&As[(mo + mi * 16 + fr) * 40 + q8];
#pragma unroll
    for (int ni = 0; ni < 4; ni++)
      bfr[ni] = *(const bf16x8*)&Bs[(no + ni * 16 + fr) * 40 + q8];
#pragma unroll
    for (int mi = 0; mi < 4; mi++)
#pragma unroll
      for (int ni = 0; ni < 4; ni++)
        acc[mi][ni] = __builtin_amdgcn_mfma_f32_16x16x32_bf16(afr[mi], bfr[ni], acc[mi][ni], 0, 0, 0);
  }

  const int cm = (ln >> 4) * 4;
  const int cn = fr;
#pragma unroll
  for (int mi = 0; mi < 4; mi++) {
#pragma unroll
    for (int ni = 0; ni < 4; ni++) {
#pragma unroll
      for (int r = 0; r < 4; r++) {
        const int grow = bm + mo + mi * 16 + cm + r;
        const int gcol = bn + no + ni * 16 + cn;
        const size_t off = (size_t)grow * N + gcol;
        const float v = acc[mi][ni][r];
        if (EPI == 0) {
          Cb[off] = f2bf(v);
        } else if (EPI == 1) {
          Cf[off] += v;
        } else {
          Cb[off] = f2bf(siluf(bf2f(Cb[off])) * v);
        }
      }
    }
  }
}

// ---------------- ba = h @ ba_w^T ----------------
__global__ __launch_bounds__(256) void ba_gemm_kernel(const float* __restrict__ h_in,
                                                      const float* __restrict__ ba_w,
                                                      float* __restrict__ ba_out) {
  __shared__ __align__(16) float hl[2048];
  __shared__ float red[32][9];
  const int t = blockIdx.x;
  const int tid = threadIdx.x;
  const float4* hr = (const float4*)(h_in + (size_t)t * DMODEL);
  ((float4*)hl)[tid] = hr[tid];
  ((float4*)hl)[tid + 256] = hr[tid + 256];
  __syncthreads();
  const int c = tid & 31;
  const int p = tid >> 5;
  const float* wrow = ba_w + (size_t)c * DMODEL + p * 256;
  const float* hrow = hl + p * 256;
  float s = 0.f;
#pragma unroll 8
  for (int k = 0; k < 256; k++) s += hrow[k] * wrow[k];
  red[c][p] = s;
  __syncthreads();
  if (tid < 32) {
    float tot = 0.f;
#pragma unroll
    for (int q = 0; q < 8; q++) tot += red[tid][q];
    ba_out[(size_t)t * 32 + tid] = tot;
  }
}

// ---------------- extract z columns from bf16 qkvz ----------------
__global__ __launch_bounds__(256) void zcopy_kernel(const unsigned short* __restrict__ qkvz,
                                                    unsigned short* __restrict__ z) {
  const int idx = blockIdx.x * 256 + threadIdx.x;
  const int t = idx >> 8;
  const int c8 = (idx & 255) * 8;
  *(uint4*)(z + (size_t)t * 2048 + c8) =
      *(const uint4*)(qkvz + (size_t)t * CQKVZ + CQKV + c8);
}

// ---------------- causal depthwise conv (K=4) + SiLU; bf16 in, fp32 out ----------------
__global__ __launch_bounds__(256) void conv_silu_kernel(const unsigned short* __restrict__ qkvz,
                                                        const float* __restrict__ conv_w,
                                                        const float* __restrict__ mask,
                                                        float* __restrict__ mixed) {
  const int idx = blockIdx.x * 256 + threadIdx.x;
  const int c4 = (idx % 1536) * 4;
  const int t = idx / 1536;
  const float4 w0 = *(const float4*)(conv_w + (size_t)c4 * 4);
  const float4 w1 = *(const float4*)(conv_w + (size_t)c4 * 4 + 4);
  const float4 w2 = *(const float4*)(conv_w + (size_t)c4 * 4 + 8);
  const float4 w3 = *(const float4*)(conv_w + (size_t)c4 * 4 + 12);
  const float wj0[4] = {w0.x, w0.y, w0.z, w0.w};
  const float wj1[4] = {w1.x, w1.y, w1.z, w1.w};
  const float wj2[4] = {w2.x, w2.y, w2.z, w2.w};
  const float wj3[4] = {w3.x, w3.y, w3.z, w3.w};
  float4 acc = make_float4(0.f, 0.f, 0.f, 0.f);
#pragma unroll
  for (int j = 0; j < 4; j++) {
    const int tt = t - 3 + j;
    if (tt < 0) continue;
    const float m = mask[tt];
    const ushort4 xb = *(const ushort4*)(qkvz + (size_t)tt * CQKVZ + c4);
    acc.x += bf2f(xb.x) * m * wj0[j];
    acc.y += bf2f(xb.y) * m * wj1[j];
    acc.z += bf2f(xb.z) * m * wj2[j];
    acc.w += bf2f(xb.w) * m * wj3[j];
  }
  acc.x = siluf(acc.x); acc.y = siluf(acc.y); acc.z = siluf(acc.z); acc.w = siluf(acc.w);
  *(float4*)(mixed + (size_t)t * CQKV + c4) = acc;
}

// ---------------- l2norm over Dk=128 for q,k heads (in place, fp32) ----------------
__global__ __launch_bounds__(256) void l2norm_kernel(float* __restrict__ mixed) {
  const int r = blockIdx.x * 4 + (threadIdx.x >> 6);
  const int lane = threadIdx.x & 63;
  const int t = r >> 5;
  const int hh = r & 31;
  float* p = mixed + (size_t)t * CQKV + hh * 128 + lane * 2;
  float2 v = *(float2*)p;
  float s = v.x * v.x + v.y * v.y;
#pragma unroll
  for (int off = 32; off > 0; off >>= 1) s += __shfl_down(s, off);
  s = __shfl(s, 0);
  const float rn = rsqrtf(s + 1e-6f);
  v.x *= rn; v.y *= rn;
  *(float2*)p = v;
}

// ---------------- beta, g ----------------
__global__ __launch_bounds__(256) void beta_g_kernel(const float* __restrict__ ba,
                                                     const float* __restrict__ A_log,
                                                     const float* __restrict__ dt_bias,
                                                     const float* __restrict__ mask,
                                                     float* __restrict__ beta,
                                                     float* __restrict__ g) {
  const int idx = blockIdx.x * 256 + threadIdx.x;
  const int t = idx >> 4;
  const int h = idx & 15;
  const float b = ba[(size_t)t * 32 + h];
  const float a = ba[(size_t)t * 32 + 16 + h];
  const float m = mask[t];
  beta[idx] = m / (1.0f + expf(-b));
  const float xx = a + dt_bias[h];
  const float sp = (xx > 20.0f) ? xx : log1pf(expf(xx));
  g[idx] = -expf(A_log[h]) * sp * m;
}

// ---------------- per-chunk cumsum of g + decay factors ----------------
__global__ __launch_bounds__(256) void gcs_kernel(const float* __restrict__ g,
                                                  float* __restrict__ gcsbuf,
                                                  float* __restrict__ edkbuf,
                                                  float* __restrict__ egqbuf,
                                                  float* __restrict__ adecbuf) {
  const int idx = blockIdx.x * 256 + threadIdx.x;  // chunk id = h*64 + n
  if (idx >= 1024) return;
  const int h = idx >> 6;
  const int n = idx & 63;
  const int t0 = n * 64;
  float s = 0.f;
  for (int i = 0; i < 64; i++) {
    s += g[(size_t)(t0 + i) * NH + h];
    gcsbuf[(size_t)idx * 64 + i] = s;
  }
  const float glast = s;
  adecbuf[idx] = __expf(glast);
  for (int i = 0; i < 64; i++) {
    const float gi = gcsbuf[(size_t)idx * 64 + i];
    edkbuf[(size_t)idx * 64 + i] = __expf(glast - gi);
    egqbuf[(size_t)idx * 64 + i] = __expf(gi) * SCALE;
  }
}

// ---------------- per-chunk: A=(k_beta k^T)*decay (strict lower), attn=(q k^T)*decay*scale ----------------
__global__ __launch_bounds__(256) void pre_attn_kernel(const float* __restrict__ mixed,
                                                       const float* __restrict__ gcsbuf,
                                                       const float* __restrict__ betabuf,
                                                       float* __restrict__ abuf,
                                                       float* __restrict__ attnbuf) {
  __shared__ __align__(16) float kl[64][132];
  __shared__ float gcs_s[64];
  __shared__ float betal[64];
  const int blk = blockIdx.x;
  const int h = blk >> 6;
  const int n = blk & 63;
  const int t0 = n * 64;
  const int tid = threadIdx.x;
  if (tid < 64) {
    gcs_s[tid] = gcsbuf[(size_t)blk * 64 + tid];
    betal[tid] = betabuf[(size_t)(t0 + tid) * NH + h];
  }
#pragma unroll
  for (int rep = 0; rep < 8; rep++) {
    const int lin = rep * 256 + tid;
    const int i = lin >> 5;
    const int d = (lin & 31) * 4;
    const float4 kv = *(const float4*)(mixed + (size_t)(t0 + i) * CQKV + 2048 + h * 128 + d);
    *(float4*)&kl[i][d] = kv;
  }
  __syncthreads();
  const int cj = tid & 15;
  const int ri = tid >> 4;
  const int i0 = ri * 4, j0 = cj * 4;
  float accA[4][4], accQ[4][4];
#pragma unroll
  for (int a = 0; a < 4; a++)
#pragma unroll
    for (int b = 0; b < 4; b++) { accA[a][b] = 0.f; accQ[a][b] = 0.f; }
  const float* qbase = mixed + (size_t)t0 * CQKV + h * 128;
#pragma unroll 4
  for (int d = 0; d < 128; d++) {
    const float kj0 = kl[j0][d], kj1 = kl[j0 + 1][d], kj2 = kl[j0 + 2][d], kj3 = kl[j0 + 3][d];
#pragma unroll
    for (int a = 0; a < 4; a++) {
      const float ka = kl[i0 + a][d];
      const float qa = qbase[(size_t)(i0 + a) * CQKV + d];
      accA[a][0] += ka * kj0; accA[a][1] += ka * kj1; accA[a][2] += ka * kj2; accA[a][3] += ka * kj3;
      accQ[a][0] += qa * kj0; accQ[a][1] += qa * kj1; accQ[a][2] += qa * kj2; accQ[a][3] += qa * kj3;
    }
  }
#pragma unroll
  for (int a = 0; a < 4; a++) {
    const int i = i0 + a;
    const float gi = gcs_s[i];
    const float bi = betal[i];
    float4 Av, Qv;
    float dec;
    dec = __expf(fminf(gi - gcs_s[j0 + 0], 0.f));
    Av.x = (i > j0 + 0) ? accA[a][0] * bi * dec : 0.f;
    Qv.x = (i >= j0 + 0) ? accQ[a][0] * dec * SCALE : 0.f;
    dec = __expf(fminf(gi - gcs_s[j0 + 1], 0.f));
    Av.y = (i > j0 + 1) ? accA[a][1] * bi * dec : 0.f;
    Qv.y = (i >= j0 + 1) ? accQ[a][1] * dec * SCALE : 0.f;
    dec = __expf(fminf(gi - gcs_s[j0 + 2], 0.f));
    Av.z = (i > j0 + 2) ? accA[a][2] * bi * dec : 0.f;
    Qv.z = (i >= j0 + 2) ? accQ[a][2] * dec * SCALE : 0.f;
    dec = __expf(fminf(gi - gcs_s[j0 + 3], 0.f));
    Av.w = (i > j0 + 3) ? accA[a][3] * bi * dec : 0.f;
    Qv.w = (i >= j0 + 3) ? accQ[a][3] * dec * SCALE : 0.f;
    *(float4*)(abuf + (size_t)blk * 4096 + i * 64 + j0) = Av;
    *(float4*)(attnbuf + (size_t)blk * 4096 + i * 64 + j0) = Qv;
  }
}

// ---------------- per-chunk: T = (I+A)^-1, then T *= beta[col] ----------------
__global__ __launch_bounds__(256) void pre_solve_kernel(const float* __restrict__ abuf,
                                                        const float* __restrict__ betabuf,
                                                        float* __restrict__ tbuf) {
  __shared__ float Al[64][65];
  __shared__ float Tl[64][65];
  const int blk = blockIdx.x;
  const int h = blk >> 6;
  const int n = blk & 63;
  const int t0 = n * 64;
  const int tid = threadIdx.x;
#pragma unroll
  for (int rep = 0; rep < 4; rep++) {
    const int lin = rep * 256 + tid;
    const int i = lin >> 4;
    const int j = (lin & 15) * 4;
    const float4 av = *(const float4*)(abuf + (size_t)blk * 4096 + i * 64 + j);
    Al[i][j] = av.x; Al[i][j + 1] = av.y; Al[i][j + 2] = av.z; Al[i][j + 3] = av.w;
  }
  __syncthreads();
  if (tid < 64) {
    const int j = tid;
    const float bj = betabuf[(size_t)(t0 + j) * NH + h];
    for (int i = 0; i < 64; i++) {
      float s = (i == j) ? 1.0f : 0.0f;
      for (int l = j; l < i; l++) s -= Al[i][l] * Tl[l][j];
      Tl[i][j] = s;
    }
    for (int i = j; i < 64; i++) Tl[i][j] *= bj;
  }
  __syncthreads();
#pragma unroll
  for (int rep = 0; rep < 4; rep++) {
    const int lin = rep * 256 + tid;
    const int i = lin >> 4;
    const int j = (lin & 15) * 4;
    float4 tv;
    tv.x = Tl[i][j]; tv.y = Tl[i][j + 1]; tv.z = Tl[i][j + 2]; tv.w = Tl[i][j + 3];
    *(float4*)(tbuf + (size_t)blk * 4096 + i * 64 + j) = tv;
  }
}

// ---------------- per-chunk: u = Tb @ v (f32) ; w = Tb @ (k * e^gcs) (bf16) ----------------
__global__ __launch_bounds__(256) void pre_uw_kernel(const float* __restrict__ mixed,
                                                     const float* __restrict__ tbuf,
                                                     const float* __restrict__ gcsbuf,
                                                     float* __restrict__ ubuf,
                                                     unsigned short* __restrict__ wbf) {
  __shared__ __align__(16) float Tl[64][68];
  __shared__ __align__(16) float xl[64][132];
  __shared__ float egcs[64];
  const int blk = blockIdx.x;
  const int h = blk >> 6;
  const int n = blk & 63;
  const int t0 = n * 64;
  const int tid = threadIdx.x;
  if (tid < 64) egcs[tid] = __expf(gcsbuf[(size_t)blk * 64 + tid]);
#pragma unroll
  for (int rep = 0; rep < 4; rep++) {
    const int lin = rep * 256 + tid;
    const int i = lin >> 4;
    const int j = (lin & 15) * 4;
    const float4 tv = *(const float4*)(tbuf + (size_t)blk * 4096 + i * 64 + j);
    *(float4*)&Tl[i][j] = tv;
  }
#pragma unroll
  for (int rep = 0; rep < 8; rep++) {
    const int lin = rep * 256 + tid;
    const int i = lin >> 5;
    const int d = (lin & 31) * 4;
    const float4 vv = *(const float4*)(mixed + (size_t)(t0 + i) * CQKV + 4096 + h * 128 + d);
    *(float4*)&xl[i][d] = vv;
  }
  __syncthreads();
  const int cgu = tid & 15;
  const int riu = tid >> 4;
  const int i0 = riu * 4;
  const int d0 = cgu * 8;
  float acc[4][8];
#pragma unroll
  for (int a = 0; a < 4; a++)
#pragma unroll
    for (int b = 0; b < 8; b++) acc[a][b] = 0.f;
#pragma unroll 2
  for (int j = 0; j < 64; j++) {
    const float tv[4] = {Tl[i0][j], Tl[i0 + 1][j], Tl[i0 + 2][j], Tl[i0 + 3][j]};
    const float4 x0 = *(const float4*)&xl[j][d0];
    const float4 x1 = *(const float4*)&xl[j][d0 + 4];
    const float xv[8] = {x0.x, x0.y, x0.z, x0.w, x1.x, x1.y, x1.z, x1.w};
#pragma unroll
    for (int a = 0; a < 4; a++)
#pragma unroll
      for (int b = 0; b < 8; b++) acc[a][b] += tv[a] * xv[b];
  }
#pragma unroll
  for (int a = 0; a < 4; a++) {
    float* up = ubuf + (size_t)(t0 + i0 + a) * 2048 + h * 128 + d0;
    *(float4*)up = make_float4(acc[a][0], acc[a][1], acc[a][2], acc[a][3]);
    *(float4*)(up + 4) = make_float4(acc[a][4], acc[a][5], acc[a][6], acc[a][7]);
  }
  __syncthreads();
#pragma unroll
  for (int rep = 0; rep < 8; rep++) {
    const int lin = rep * 256 + tid;
    const int i = lin >> 5;
    const int d = (lin & 31) * 4;
    float4 kv = *(const float4*)(mixed + (size_t)(t0 + i) * CQKV + 2048 + h * 128 + d);
    const float e = egcs[i];
    kv.x *= e; kv.y *= e; kv.z *= e; kv.w *= e;
    *(float4*)&xl[i][d] = kv;
  }
  __syncthreads();
#pragma unroll
  for (int a = 0; a < 4; a++)
#pragma unroll
    for (int b = 0; b < 8; b++) acc[a][b] = 0.f;
#pragma unroll 2
  for (int j = 0; j < 64; j++) {
    const float tv[4] = {Tl[i0][j], Tl[i0 + 1][j], Tl[i0 + 2][j], Tl[i0 + 3][j]};
    const float4 x0 = *(const float4*)&xl[j][d0];
    const float4 x1 = *(const float4*)&xl[j][d0 + 4];
    const float xv[8] = {x0.x, x0.y, x0.z, x0.w, x1.x, x1.y, x1.z, x1.w};
#pragma unroll
    for (int a = 0; a < 4; a++)
#pragma unroll
      for (int b = 0; b < 8; b++) acc[a][b] += tv[a] * xv[b];
  }
#pragma unroll
  for (int a = 0; a < 4; a++) {
    unsigned short* wp = wbf + (size_t)(t0 + i0 + a) * 2048 + h * 128 + d0;
    *(ushort4*)wp = pack4(acc[a][0], acc[a][1], acc[a][2], acc[a][3]);
    *(ushort4*)(wp + 4) = pack4(acc[a][4], acc[a][5], acc[a][6], acc[a][7]);
  }
}

// ---------------- per-chunk: kdT[blk][d][l] = bf16( k[t0+l][d] * edk[blk][l] ) ----------------
__global__ __launch_bounds__(256) void ktrans_kernel(const float* __restrict__ mixed,
                                                     const float* __restrict__ edkbuf,
                                                     unsigned short* __restrict__ kdT) {
  __shared__ __align__(16) float kl[64][132];
  __shared__ float edk_s[64];
  const int blk = blockIdx.x;
  const int h = blk >> 6;
  const int n = blk & 63;
  const int t0 = n * 64;
  const int tid = threadIdx.x;
  if (tid < 64) edk_s[tid] = edkbuf[(size_t)blk * 64 + tid];
#pragma unroll
  for (int q = 0; q < 8; q++) {
    const int idx = tid + q * 256;
    const int l = idx >> 5, c4 = (idx & 31) * 4;
    *(float4*)&kl[l][c4] = *(const float4*)(mixed + (size_t)(t0 + l) * CQKV + 2048 + h * 128 + c4);
  }
  __syncthreads();
#pragma unroll
  for (int q = 0; q < 4; q++) {
    const int idx = tid + q * 256;
    const int d = idx >> 3, l8 = (idx & 7) * 8;
    float v[8];
#pragma unroll
    for (int j = 0; j < 8; j++) v[j] = kl[l8 + j][d] * edk_s[l8 + j];
    unsigned short* p = kdT + (size_t)blk * 8192 + d * 64 + l8;
    *(ushort4*)p = pack4(v[0], v[1], v[2], v[3]);
    *(ushort4*)(p + 4) = pack4(v[4], v[5], v[6], v[7]);
  }
}

// ---------------- MFMA sequential scan: 1 block = 1 head, 8 waves, S^T held in accumulators ----------------
// per chunk n: ST_out[blk] = S_n^T (bf16);  vt_out[blk] = v_new^T (bf16);  S_{n+1} = a*S_n + kdec^T @ v_new
// state accum layout: acc2[ct] = C[m = d-tile wv][n = c-tile ct] fragments of S[d][c].
__global__ __launch_bounds__(512) void scan_kernel(const unsigned short* __restrict__ wbf,
                                                   const unsigned short* __restrict__ kdT,
                                                   const float* __restrict__ ubuf,
                                                   const float* __restrict__ adecbuf,
                                                   unsigned short* __restrict__ STb,
                                                   unsigned short* __restrict__ vtb) {
  __shared__ __align__(16) unsigned short w_lds[64 * 128];   // [l][d] bf16, xor-swizzled
  __shared__ __align__(16) unsigned short kT_lds[128 * 64];  // [d][l] bf16, xor-swizzled
  __shared__ __align__(16) unsigned short st_lds[128 * 128]; // [c][d] bf16, xor-swizzled
  __shared__ __align__(16) unsigned short vt_lds[128 * 64];  // [c][l] bf16, xor-swizzled
  __shared__ __align__(16) float u_lds[64 * 132];            // [l][c] f32 (pad 132)
  const int h = blockIdx.x;
  const int tid = threadIdx.x;
  const int ln = tid & 63;
  const int wv = tid >> 6;   // 0..7
  const int fr = ln & 15;
  const int g = ln >> 4;     // 0..3
  const int lt = wv & 3;     // phase-B l-tile
  const int ch = wv >> 2;    // phase-B c-half
  const f32x4 zero = {0.f, 0.f, 0.f, 0.f};

  uint4 wreg[2], kreg[2];
  float4 ureg[4];
  // prefetch chunk 0
#pragma unroll
  for (int q = 0; q < 2; q++) {
    const int idx = tid + q * 512;
    const int row = idx >> 4, c8 = (idx & 15) * 8;
    wreg[q] = *(const uint4*)(wbf + (size_t)row * 2048 + h * 128 + c8);
    const int d = idx >> 3, l8 = (idx & 7) * 8;
    kreg[q] = *(const uint4*)(kdT + (size_t)(h * 64) * 8192 + d * 64 + l8);
  }
#pragma unroll
  for (int q = 0; q < 4; q++) {
    const int idx = tid + q * 512;
    const int row = idx >> 5, c4 = (idx & 31) * 4;
    ureg[q] = *(const float4*)(ubuf + (size_t)row * 2048 + h * 128 + c4);
  }

  f32x4 acc2[8];
#pragma unroll
  for (int ct = 0; ct < 8; ct++) acc2[ct] = zero;

  for (int n = 0; n < 64; n++) {
    const int blk = h * 64 + n;
    // ---- step 1: stage w,u for chunk n; dump S_n^T -> st_lds ----
#pragma unroll
    for (int q = 0; q < 2; q++) {
      const int idx = tid + q * 512;
      const int row = idx >> 4, c8 = (idx & 15) * 8;
      *(uint4*)&w_lds[row * 128 + (((c8 >> 3) ^ (row & 7)) << 3)] = wreg[q];
    }
#pragma unroll
    for (int q = 0; q < 4; q++) {
      const int idx = tid + q * 512;
      const int row = idx >> 5, c4 = (idx & 31) * 4;
      *(float4*)&u_lds[row * 132 + c4] = ureg[q];
    }
    {
      const int db = wv * 16 + g * 4;
#pragma unroll
      for (int ct = 0; ct < 8; ct++) {
        const int c = ct * 16 + fr;
        *(ushort4*)&st_lds[c * 128 + (((db >> 3) ^ (c & 7)) << 3) + (db & 7)] =
            pack4(acc2[ct][0], acc2[ct][1], acc2[ct][2], acc2[ct][3]);
      }
    }
    __syncthreads();  // (A)
    // ---- step 2: stage kT; prefetch n+1; export S_n; v_new = u - w@S ----
#pragma unroll
    for (int q = 0; q < 2; q++) {
      const int idx = tid + q * 512;
      const int d = idx >> 3, l8 = (idx & 7) * 8;
      *(uint4*)&kT_lds[d * 64 + (((l8 >> 3) ^ (d & 7)) << 3)] = kreg[q];
    }
    if (n < 63) {
      const int t0n = (n + 1) * 64;
#pragma unroll
      for (int q = 0; q < 2; q++) {
        const int idx = tid + q * 512;
        const int row = idx >> 4, c8 = (idx & 15) * 8;
        wreg[q] = *(const uint4*)(wbf + (size_t)(t0n + row) * 2048 + h * 128 + c8);
        const int d = idx >> 3, l8 = (idx & 7) * 8;
        kreg[q] = *(const uint4*)(kdT + (size_t)(blk + 1) * 8192 + d * 64 + l8);
      }
#pragma unroll
      for (int q = 0; q < 4; q++) {
        const int idx = tid + q * 512;
        const int row = idx >> 5, c4 = (idx & 31) * 4;
        ureg[q] = *(const float4*)(ubuf + (size_t)(t0n + row) * 2048 + h * 128 + c4);
      }
    }
#pragma unroll
    for (int q = 0; q < 4; q++) {  // S_n^T -> global (unswizzle)
      const int idx = tid + q * 512;
      const int c = idx >> 4, dg = idx & 15;
      *(uint4*)(STb + (size_t)blk * 16384 + c * 128 + dg * 8) =
          *(const uint4*)&st_lds[c * 128 + ((dg ^ (c & 7)) << 3)];
    }
    f32x4 acc1[4];
#pragma unroll
    for (int ct = 0; ct < 4; ct++) acc1[ct] = zero;
#pragma unroll
    for (int ks = 0; ks < 4; ks++) {
      const int kb = ks * 4 + g;
      const int ar = lt * 16 + fr;
      const bf16x8 a = *(const bf16x8*)&w_lds[ar * 128 + ((kb ^ (ar & 7)) << 3)];
#pragma unroll
      for (int ct = 0; ct < 4; ct++) {
        const int c = (ch * 4 + ct) * 16 + fr;
        const bf16x8 b = *(const bf16x8*)&st_lds[c * 128 + ((kb ^ (c & 7)) << 3)];
        acc1[ct] = __builtin_amdgcn_mfma_f32_16x16x32_bf16(a, b, acc1[ct], 0, 0, 0);
      }
    }
    {
      const int lb = lt * 16 + g * 4;
#pragma unroll
      for (int ct = 0; ct < 4; ct++) {
        const int c = (ch * 4 + ct) * 16 + fr;
        const float v0 = u_lds[(lb + 0) * 132 + c] - acc1[ct][0];
        const float v1 = u_lds[(lb + 1) * 132 + c] - acc1[ct][1];
        const float v2 = u_lds[(lb + 2) * 132 + c] - acc1[ct][2];
        const float v3 = u_lds[(lb + 3) * 132 + c] - acc1[ct][3];
        *(ushort4*)&vt_lds[c * 64 + (((lb >> 3) ^ (c & 7)) << 3) + (lb & 7)] =
            pack4(v0, v1, v2, v3);
      }
    }
    const float adec = adecbuf[blk];
    __syncthreads();  // (B)
    // ---- step 3: export v_new^T; S = a*S + kdec^T @ v_new ----
#pragma unroll
    for (int q = 0; q < 2; q++) {
      const int idx = tid + q * 512;
      const int c = idx >> 3, lg = idx & 7;
      *(uint4*)(vtb + (size_t)blk * 8192 + c * 64 + lg * 8) =
          *(const uint4*)&vt_lds[c * 64 + ((lg ^ (c & 7)) << 3)];
    }
#pragma unroll
    for (int ct = 0; ct < 8; ct++) {
      acc2[ct][0] *= adec; acc2[ct][1] *= adec; acc2[ct][2] *= adec; acc2[ct][3] *= adec;
    }
#pragma unroll
    for (int ks = 0; ks < 2; ks++) {
      const int kb = ks * 4 + g;
      const int ar = wv * 16 + fr;
      const bf16x8 a = *(const bf16x8*)&kT_lds[ar * 64 + ((kb ^ (ar & 7)) << 3)];
#pragma unroll
      for (int ct = 0; ct < 8; ct++) {
        const int c = ct * 16 + fr;
        const bf16x8 b = *(const bf16x8*)&vt_lds[c * 64 + ((kb ^ (c & 7)) << 3)];
        acc2[ct] = __builtin_amdgcn_mfma_f32_16x16x32_bf16(a, b, acc2[ct], 0, 0, 0);
      }
    }
  }
}

// ---------------- MFMA o-compute + fused gated RMSNorm ----------------
// o[i][c] = sum_d q̂[i][d]*ST[c][d] + sum_l attn[i][l]*vt[c][l]
// ob[i][c] = bf16( o * rsqrt(mean_c(o^2)+eps) * w[c] * silu(z) )
__global__ __launch_bounds__(256) void ocomp_kernel(const float* __restrict__ mixed,
                                                    const unsigned short* __restrict__ STbuf,
                                                    const unsigned short* __restrict__ vtbuf,
                                                    const float* __restrict__ attnbuf,
                                                    const float* __restrict__ egqbuf,
                                                    const unsigned short* __restrict__ zb,
                                                    const float* __restrict__ onw,
                                                    unsigned short* __restrict__ ob) {
  __shared__ __align__(16) unsigned short STl[128 * 128];  // [c][d]
  __shared__ __align__(16) unsigned short vtl[128 * 64];   // [c][l]
  __shared__ __align__(16) unsigned short ql[64 * 128];    // [i][d]
  __shared__ __align__(16) unsigned short al[64 * 64];     // [i][l]
  const int blk = blockIdx.x;
  const int h = blk >> 6;
  const int n = blk & 63;
  const int t0 = n * 64;
  const int tid = threadIdx.x;
#pragma unroll
  for (int q = 0; q < 8; q++) {
    const int idx = tid + q * 256;
    const int c = idx >> 4, dg = idx & 15;
    *(uint4*)&STl[c * 128 + ((dg ^ (c & 7)) << 3)] =
        *(const uint4*)(STbuf + (size_t)blk * 16384 + c * 128 + dg * 8);
  }
#pragma unroll
  for (int q = 0; q < 4; q++) {
    const int idx = tid + q * 256;
    const int c = idx >> 3, lg = idx & 7;
    *(uint4*)&vtl[c * 64 + ((lg ^ (c & 7)) << 3)] =
        *(const uint4*)(vtbuf + (size_t)blk * 8192 + c * 64 + lg * 8);
  }
#pragma unroll
  for (int q = 0; q < 8; q++) {
    const int idx = tid + q * 256;
    const int i = idx >> 5, c4 = (idx & 31) * 4;
    const float eg = egqbuf[(size_t)blk * 64 + i];
    const float4 v = *(const float4*)(mixed + (size_t)(t0 + i) * CQKV + h * 128 + c4);
    *(ushort4*)&ql[i * 128 + (((c4 >> 3) ^ (i & 7)) << 3) + (c4 & 7)] =
        pack4(v.x * eg, v.y * eg, v.z * eg, v.w * eg);
  }
#pragma unroll
  for (int q = 0; q < 4; q++) {
    const int idx = tid + q * 256;
    const int i = idx >> 4, l4 = (idx & 15) * 4;
    const float4 v = *(const float4*)(attnbuf + (size_t)blk * 4096 + i * 64 + l4);
    *(ushort4*)&al[i * 64 + (((l4 >> 3) ^ (i & 7)) << 3) + (l4 & 7)] =
        pack4(v.x, v.y, v.z, v.w);
  }
  __syncthreads();
  const int ln = tid & 63;
  const int wv = tid >> 6;
  const int fr = ln & 15;
  const int g = ln >> 4;
  const int i0 = wv * 16;
  f32x4 acc[8];
  const f32x4 zero = {0.f, 0.f, 0.f, 0.f};
#pragma unroll
  for (int nt = 0; nt < 8; nt++) acc[nt] = zero;
#pragma unroll
  for (int ks = 0; ks < 4; ks++) {
    const int kb = ks * 4 + g;
    const int ar = i0 + fr;
    const bf16x8 a = *(const bf16x8*)&ql[ar * 128 + ((kb ^ (ar & 7)) << 3)];
#pragma unroll
    for (int nt = 0; nt < 8; nt++) {
      const int c = nt * 16 + fr;
      const bf16x8 b = *(const bf16x8*)&STl[c * 128 + ((kb ^ (c & 7)) << 3)];
      acc[nt] = __builtin_amdgcn_mfma_f32_16x16x32_bf16(a, b, acc[nt], 0, 0, 0);
    }
  }
#pragma unroll
  for (int ks = 0; ks < 2; ks++) {
    const int kb = ks * 4 + g;
    const int ar = i0 + fr;
    const bf16x8 a = *(const bf16x8*)&al[ar * 64 + ((kb ^ (ar & 7)) << 3)];
#pragma unroll
    for (int nt = 0; nt < 8; nt++) {
      const int c = nt * 16 + fr;
      const bf16x8 b = *(const bf16x8*)&vtl[c * 64 + ((kb ^ (c & 7)) << 3)];
      acc[nt] = __builtin_amdgcn_mfma_f32_16x16x32_bf16(a, b, acc[nt], 0, 0, 0);
    }
  }
  // fused gated RMSNorm: rows i = i0 + g*4 + r ; cols c = fr + 16*nt
  float s0 = 0.f, s1 = 0.f, s2 = 0.f, s3 = 0.f;
#pragma unroll
  for (int nt = 0; nt < 8; nt++) {
    s0 += acc[nt][0] * acc[nt][0];
    s1 += acc[nt][1] * acc[nt][1];
    s2 += acc[nt][2] * acc[nt][2];
    s3 += acc[nt][3] * acc[nt][3];
  }
#pragma unroll
  for (int m = 1; m < 16; m <<= 1) {
    s0 += __shfl_xor(s0, m);
    s1 += __shfl_xor(s1, m);
    s2 += __shfl_xor(s2, m);
    s3 += __shfl_xor(s3, m);
  }
  float rn[4];
  rn[0] = rsqrtf(s0 * (1.0f / 128.0f) + 1e-5f);
  rn[1] = rsqrtf(s1 * (1.0f / 128.0f) + 1e-5f);
  rn[2] = rsqrtf(s2 * (1.0f / 128.0f) + 1e-5f);
  rn[3] = rsqrtf(s3 * (1.0f / 128.0f) + 1e-5f);
#pragma unroll
  for (int nt = 0; nt < 8; nt++) {
    const int c = nt * 16 + fr;
    const float wn = onw[c];
#pragma unroll
    for (int r = 0; r < 4; r++) {
      const size_t off = (size_t)(t0 + i0 + g * 4 + r) * 2048 + h * 128 + c;
      const float zz = siluf(bf2f(zb[off]));
      ob[off] = f2bf(acc[nt][r] * rn[r] * wn * zz);
    }
  }
}

// ---------------- helpers ----------------
__global__ __launch_bounds__(256) void copy_kernel(const float* __restrict__ in,
                                                   float* __restrict__ out) {
  const int i = blockIdx.x * 256 + threadIdx.x;
  ((float4*)out)[i] = ((const float4*)in)[i];
}

extern "C" void kernel_launch(void* const* d_in, const int* in_sizes, int n_in,
                              void* d_out, int out_size, void* d_ws, size_t ws_size,
                              hipStream_t stream) {
  (void)in_sizes; (void)n_in; (void)out_size;
  const float* x        = (const float*)d_in[0];
  const float* mask     = (const float*)d_in[1];
  const float* ln1_w    = (const float*)d_in[2];
  const float* qkvz_w   = (const float*)d_in[3];
  const float* ba_w     = (const float*)d_in[4];
  const float* conv_w   = (const float*)d_in[5];
  const float* A_log    = (const float*)d_in[6];
  const float* dt_bias  = (const float*)d_in[7];
  const float* o_norm_w = (const float*)d_in[8];
  const float* out_w    = (const float*)d_in[9];
  const float* ln2_w    = (const float*)d_in[10];
  const float* gate_w   = (const float*)d_in[11];
  const float* up_w     = (const float*)d_in[12];
  const float* down_w   = (const float*)d_in[13];
  float* out = (float*)d_out;

  const size_t NEED_BYTES = (size_t)75825152 * 4;
  if (ws_size < NEED_BYTES) return;

  float* ws = (float*)d_ws;
  // [0, 25165824): mixed_f32 (phase A)  ->  Wg/Wu/Wd bf16 (MLP phase)
  float* mixed_buf = ws;
  unsigned short* Wg = (unsigned short*)ws;
  unsigned short* Wu = (unsigned short*)(ws + 8388608);
  unsigned short* Wd = (unsigned short*)(ws + 16777216);
  // [25165824, 41943040): qkvz_bf16 -> u f32 / wbf bf16 / kdT bf16 -> gate/comb bf16
  unsigned short* qkvz_bf = (unsigned short*)(ws + 25165824);
  float* u_buf = ws + 25165824;                              // 8388608 f
  unsigned short* wbf = (unsigned short*)(ws + 33554432);    // 4096x2048 bf16
  unsigned short* kdT = (unsigned short*)(ws + 37748736);    // 1024x128x64 bf16
  unsigned short* gate_bf = (unsigned short*)(ws + 25165824);
  // [41943040, 46137344): z bf16
  unsigned short* z_bf = (unsigned short*)(ws + 41943040);
  // [46137344, 54525952): h_f32 -> a_buf -> vt_buf ; t_buf
  float* h_buf = ws + 46137344;
  float* a_buf = ws + 46137344;
  unsigned short* vt_buf = (unsigned short*)(ws + 46137344); // 1024x128x64 bf16
  float* t_buf = ws + 50331648;
  // [54525952, 58720256): h_bf16 -> ob bf16 -> h2_bf16
  unsigned short* h_bf  = (unsigned short*)(ws + 54525952);
  unsigned short* ob    = (unsigned short*)(ws + 54525952);
  unsigned short* h2_bf = (unsigned short*)(ws + 54525952);
  // [58720256, 62914560): attn f32
  float* attn_buf = ws + 58720256;
  // [62914560, 71303168): Wq bf16 -> STbuf bf16 (1024 x 128 x 128, S^T layout [c][d])
  unsigned short* Wq = (unsigned short*)(ws + 62914560);
  unsigned short* ST_buf = (unsigned short*)(ws + 62914560);
  // [71303168, 73400320): Wo bf16
  unsigned short* Wo = (unsigned short*)(ws + 71303168);
  // smalls
  float* ba_buf   = ws + 73400320;
  float* beta_buf = ws + 73531392;
  float* g_buf    = ws + 73596928;
  float* gcs_buf  = ws + 73662464;
  float* edk_buf  = ws + 73728000;   // [1024][64]
  float* egq_buf  = ws + 73793536;   // [1024][64]
  float* adec_buf = ws + 73859072;   // [1024]

  rmsnorm_kernel<1><<<4096, 256, 0, stream>>>(x, ln1_w, h_buf, h_bf);
  f2b_kernel<<<8192, 256, 0, stream>>>(qkvz_w, Wq);
  gemm_bf16_kernel<0><<<dim3(64, 32), 256, 0, stream>>>(h_bf, Wq, nullptr, qkvz_bf, 4096, 8192, 2048);
  ba_gemm_kernel<<<4096, 256, 0, stream>>>(h_buf, ba_w, ba_buf);
  zcopy_kernel<<<4096, 256, 0, stream>>>(qkvz_bf, z_bf);
  conv_silu_kernel<<<24576, 256, 0, stream>>>(qkvz_bf, conv_w, mask, mixed_buf);
  l2norm_kernel<<<32768, 256, 0, stream>>>(mixed_buf);
  beta_g_kernel<<<256, 256, 0, stream>>>(ba_buf, A_log, dt_bias, mask, beta_buf, g_buf);
  gcs_kernel<<<4, 256, 0, stream>>>(g_buf, gcs_buf, edk_buf, egq_buf, adec_buf);
  pre_attn_kernel<<<1024, 256, 0, stream>>>(mixed_buf, gcs_buf, beta_buf, a_buf, attn_buf);
  pre_solve_kernel<<<1024, 256, 0, stream>>>(a_buf, beta_buf, t_buf);
  pre_uw_kernel<<<1024, 256, 0, stream>>>(mixed_buf, t_buf, gcs_buf, u_buf, wbf);
  ktrans_kernel<<<1024, 256, 0, stream>>>(mixed_buf, edk_buf, kdT);
  // MFMA sequential scan: 16 heads, state in accumulators
  scan_kernel<<<16, 512, 0, stream>>>(wbf, kdT, u_buf, adec_buf, ST_buf, vt_buf);
  // MFMA o computation + fused gated RMSNorm
  ocomp_kernel<<<1024, 256, 0, stream>>>(mixed_buf, ST_buf, vt_buf, attn_buf, egq_buf,
                                         z_bf, o_norm_w, ob);
  // weight converts for the back half (mixed now dead)
  f2b_kernel<<<8192, 256, 0, stream>>>(gate_w, Wg);
  f2b_kernel<<<8192, 256, 0, stream>>>(up_w, Wu);
  f2b_kernel<<<8192, 256, 0, stream>>>(down_w, Wd);
  f2b_kernel<<<2048, 256, 0, stream>>>(out_w, Wo);
  copy_kernel<<<8192, 256, 0, stream>>>(x, out);
  gemm_bf16_kernel<1><<<dim3(16, 32), 256, 0, stream>>>(ob, Wo, out, nullptr, 4096, 2048, 2048);
  rmsnorm_kernel<2><<<4096, 256, 0, stream>>>(out, ln2_w, nullptr, h2_bf);
  gemm_bf16_kernel<0><<<dim3(64, 32), 256, 0, stream>>>(h2_bf, Wg, nullptr, gate_bf, 4096, 8192, 2048);
  gemm_bf16_kernel<2><<<dim3(64, 32), 256, 0, stream>>>(h2_bf, Wu, nullptr, gate_bf, 4096, 8192, 2048);
  gemm_bf16_kernel<1><<<dim3(16, 32), 256, 0, stream>>>(gate_bf, Wd, out, nullptr, 4096, 2048, 8192);
}

// Round 2
// 1766.699 us; speedup vs baseline: 1.1182x; 1.0116x over previous
//
#include <hip/hip_runtime.h>
#include <math.h>

#define T_LEN 4096
#define DMODEL 2048
#define NH 16
#define CQKV 6144
#define CQKVZ 8192
#define SCALE 0.08838834764831845f   // 128^-0.5

using bf16x8 = __attribute__((ext_vector_type(8))) short;
using f32x4  = __attribute__((ext_vector_type(4))) float;

__device__ __forceinline__ float siluf(float x) { return x / (1.0f + __expf(-x)); }

__device__ __forceinline__ unsigned short f2bf(float f) {  // RNE
  unsigned int u = __float_as_uint(f);
  u = (u + 0x7FFFu + ((u >> 16) & 1u)) >> 16;
  return (unsigned short)u;
}
__device__ __forceinline__ float bf2f(unsigned short u) {
  return __uint_as_float(((unsigned int)u) << 16);
}
__device__ __forceinline__ ushort4 pack4(float a, float b, float c, float d) {
  ushort4 r; r.x = f2bf(a); r.y = f2bf(b); r.z = f2bf(c); r.w = f2bf(d); return r;
}

// async global->LDS, 16 bytes per lane; LDS dest must be wave-uniform base (+ lane*16 implicit)
__device__ __forceinline__ void gl_lds16(const unsigned short* g, unsigned short* l) {
  __builtin_amdgcn_global_load_lds(
      (const __attribute__((address_space(1))) void*)g,
      (__attribute__((address_space(3))) void*)l, 16, 0, 0);
}

// ---------------- RMSNorm over D=2048; MODE: 1 = f32+bf16, 2 = bf16 only ----------------
template<int MODE>
__global__ __launch_bounds__(256) void rmsnorm_kernel(const float* __restrict__ x,
                                                      const float* __restrict__ w,
                                                      float* __restrict__ outf,
                                                      unsigned short* __restrict__ outb) {
  const int t = blockIdx.x;
  const int tid = threadIdx.x;
  const float4* xr = (const float4*)(x + (size_t)t * DMODEL);
  float4 v0 = xr[tid];
  float4 v1 = xr[tid + 256];
  float s = v0.x*v0.x + v0.y*v0.y + v0.z*v0.z + v0.w*v0.w
          + v1.x*v1.x + v1.y*v1.y + v1.z*v1.z + v1.w*v1.w;
#pragma unroll
  for (int off = 32; off > 0; off >>= 1) s += __shfl_down(s, off);
  __shared__ float red[4];
  if ((tid & 63) == 0) red[tid >> 6] = s;
  __syncthreads();
  const float tot = red[0] + red[1] + red[2] + red[3];
  const float r = rsqrtf(tot * (1.0f / DMODEL) + 1e-5f);
  const float4* wr = (const float4*)w;
  const float4 w0 = wr[tid], w1 = wr[tid + 256];
  float4 o0, o1;
  o0.x = v0.x*r*w0.x; o0.y = v0.y*r*w0.y; o0.z = v0.z*r*w0.z; o0.w = v0.w*r*w0.w;
  o1.x = v1.x*r*w1.x; o1.y = v1.y*r*w1.y; o1.z = v1.z*r*w1.z; o1.w = v1.w*r*w1.w;
  if (MODE == 1) {
    float4* orow = (float4*)(outf + (size_t)t * DMODEL);
    orow[tid] = o0;
    orow[tid + 256] = o1;
  }
  ushort4* brow = (ushort4*)(outb + (size_t)t * DMODEL);
  brow[tid] = pack4(o0.x, o0.y, o0.z, o0.w);
  brow[tid + 256] = pack4(o1.x, o1.y, o1.z, o1.w);
}

// ---------------- fp32 -> bf16 bulk convert ----------------
__global__ __launch_bounds__(256) void f2b_kernel(const float* __restrict__ in,
                                                  unsigned short* __restrict__ out) {
  const size_t i = (size_t)blockIdx.x * 256 + threadIdx.x;
  const float4 a = ((const float4*)in)[2 * i];
  const float4 b = ((const float4*)in)[2 * i + 1];
  ((ushort4*)out)[2 * i] = pack4(a.x, a.y, a.z, a.w);
  ((ushort4*)out)[2 * i + 1] = pack4(b.x, b.y, b.z, b.w);
}

// ---------------- bf16 MFMA GEMM (m97 structure): C[M][N] = A[M][K] * B[N][K]^T ----------------
// global_load_lds width=16 staging into linear [128][32] LDS tiles; single buffer, 2 barriers/K-step.
// EPI: 0 = bf16 store, 1 = fp32 accumulate, 2 = silu(gate)*acc -> bf16 in place
template<int EPI>
__global__ __launch_bounds__(256) void gemm_bf16_kernel(const unsigned short* __restrict__ A,
                                                        const unsigned short* __restrict__ B,
                                                        float* __restrict__ Cf,
                                                        unsigned short* __restrict__ Cb,
                                                        int M, int N, int K) {
  __shared__ __align__(16) unsigned short As[128 * 32];
  __shared__ __align__(16) unsigned short Bs[128 * 32];
  // XCD-chunked bijective block swizzle (all grids have nwg % 8 == 0)
  const int gx = gridDim.x;
  const int nwg = gx * gridDim.y;
  int bid = blockIdx.y * gx + blockIdx.x;
  const int cpx = nwg >> 3;
  bid = (bid & 7) * cpx + (bid >> 3);
  const int bm = (bid / gx) * 128;
  const int bn = (bid % gx) * 128;
  const int tid = threadIdx.x;
  const int wv = tid >> 6;
  const int ln = tid & 63;
  // staging map: issue r in {0,1}: lane covers row = r*64 + wv*16 + (ln>>2), chunk (ln&3)*8 shorts
  const int srow = wv * 16 + (ln >> 2);
  const int scol = (ln & 3) * 8;
  const unsigned short* Ag = A + (size_t)(bm + srow) * K + scol;
  const unsigned short* Bg = B + (size_t)(bn + srow) * K + scol;
  const size_t rstep = (size_t)64 * K;
  unsigned short* AsW = &As[wv * 512];   // wave-uniform LDS base (wv*16 rows * 32)
  unsigned short* BsW = &Bs[wv * 512];
  const int mo = (wv >> 1) * 64;
  const int no = (wv & 1) * 64;
  const int fr = ln & 15;
  const int q8 = (ln >> 4) * 8;

  f32x4 acc[4][4];
  const f32x4 zero = {0.f, 0.f, 0.f, 0.f};
#pragma unroll
  for (int mi = 0; mi < 4; mi++)
#pragma unroll
    for (int ni = 0; ni < 4; ni++) acc[mi][ni] = zero;

  for (int k0 = 0; k0 < K; k0 += 32) {
    __syncthreads();   // all waves done reading As/Bs from previous step
    gl_lds16(Ag + k0, AsW);
    gl_lds16(Ag + rstep + k0, AsW + 2048);
    gl_lds16(Bg + k0, BsW);
    gl_lds16(Bg + rstep + k0, BsW + 2048);
    __syncthreads();   // vmcnt(0) drain + barrier: tiles resident
    bf16x8 afr[4], bfr[4];
#pragma unroll
    for (int mi = 0; mi < 4; mi++)
      afr[mi] = *(const bf16x8*)&As[(mo + mi * 16 + fr) * 32 + q8];
#pragma unroll
    for (int ni = 0; ni < 4; ni++)
      bfr[ni] = *(const bf16x8*)&Bs[(no + ni * 16 + fr) * 32 + q8];
#pragma unroll
    for (int mi = 0; mi < 4; mi++)
#pragma unroll
      for (int ni = 0; ni < 4; ni++)
        acc[mi][ni] = __builtin_amdgcn_mfma_f32_16x16x32_bf16(afr[mi], bfr[ni], acc[mi][ni], 0, 0, 0);
  }

  const int cm = (ln >> 4) * 4;
  const int cn = fr;
#pragma unroll
  for (int mi = 0; mi < 4; mi++) {
#pragma unroll
    for (int ni = 0; ni < 4; ni++) {
#pragma unroll
      for (int r = 0; r < 4; r++) {
        const int grow = bm + mo + mi * 16 + cm + r;
        const int gcol = bn + no + ni * 16 + cn;
        const size_t off = (size_t)grow * N + gcol;
        const float v = acc[mi][ni][r];
        if (EPI == 0) {
          Cb[off] = f2bf(v);
        } else if (EPI == 1) {
          Cf[off] += v;
        } else {
          Cb[off] = f2bf(siluf(bf2f(Cb[off])) * v);
        }
      }
    }
  }
}

// ---------------- ba = h @ ba_w^T ----------------
__global__ __launch_bounds__(256) void ba_gemm_kernel(const float* __restrict__ h_in,
                                                      const float* __restrict__ ba_w,
                                                      float* __restrict__ ba_out) {
  __shared__ __align__(16) float hl[2048];
  __shared__ float red[32][9];
  const int t = blockIdx.x;
  const int tid = threadIdx.x;
  const float4* hr = (const float4*)(h_in + (size_t)t * DMODEL);
  ((float4*)hl)[tid] = hr[tid];
  ((float4*)hl)[tid + 256] = hr[tid + 256];
  __syncthreads();
  const int c = tid & 31;
  const int p = tid >> 5;
  const float* wrow = ba_w + (size_t)c * DMODEL + p * 256;
  const float* hrow = hl + p * 256;
  float s = 0.f;
#pragma unroll 8
  for (int k = 0; k < 256; k++) s += hrow[k] * wrow[k];
  red[c][p] = s;
  __syncthreads();
  if (tid < 32) {
    float tot = 0.f;
#pragma unroll
    for (int q = 0; q < 8; q++) tot += red[tid][q];
    ba_out[(size_t)t * 32 + tid] = tot;
  }
}

// ---------------- extract z columns from bf16 qkvz ----------------
__global__ __launch_bounds__(256) void zcopy_kernel(const unsigned short* __restrict__ qkvz,
                                                    unsigned short* __restrict__ z) {
  const int idx = blockIdx.x * 256 + threadIdx.x;
  const int t = idx >> 8;
  const int c8 = (idx & 255) * 8;
  *(uint4*)(z + (size_t)t * 2048 + c8) =
      *(const uint4*)(qkvz + (size_t)t * CQKVZ + CQKV + c8);
}

// ---------------- causal depthwise conv (K=4) + SiLU; bf16 in, fp32 out ----------------
__global__ __launch_bounds__(256) void conv_silu_kernel(const unsigned short* __restrict__ qkvz,
                                                        const float* __restrict__ conv_w,
                                                        const float* __restrict__ mask,
                                                        float* __restrict__ mixed) {
  const int idx = blockIdx.x * 256 + threadIdx.x;
  const int c4 = (idx % 1536) * 4;
  const int t = idx / 1536;
  const float4 w0 = *(const float4*)(conv_w + (size_t)c4 * 4);
  const float4 w1 = *(const float4*)(conv_w + (size_t)c4 * 4 + 4);
  const float4 w2 = *(const float4*)(conv_w + (size_t)c4 * 4 + 8);
  const float4 w3 = *(const float4*)(conv_w + (size_t)c4 * 4 + 12);
  const float wj0[4] = {w0.x, w0.y, w0.z, w0.w};
  const float wj1[4] = {w1.x, w1.y, w1.z, w1.w};
  const float wj2[4] = {w2.x, w2.y, w2.z, w2.w};
  const float wj3[4] = {w3.x, w3.y, w3.z, w3.w};
  float4 acc = make_float4(0.f, 0.f, 0.f, 0.f);
#pragma unroll
  for (int j = 0; j < 4; j++) {
    const int tt = t - 3 + j;
    if (tt < 0) continue;
    const float m = mask[tt];
    const ushort4 xb = *(const ushort4*)(qkvz + (size_t)tt * CQKVZ + c4);
    acc.x += bf2f(xb.x) * m * wj0[j];
    acc.y += bf2f(xb.y) * m * wj1[j];
    acc.z += bf2f(xb.z) * m * wj2[j];
    acc.w += bf2f(xb.w) * m * wj3[j];
  }
  acc.x = siluf(acc.x); acc.y = siluf(acc.y); acc.z = siluf(acc.z); acc.w = siluf(acc.w);
  *(float4*)(mixed + (size_t)t * CQKV + c4) = acc;
}

// ---------------- l2norm over Dk=128 for q,k heads (in place, fp32) ----------------
__global__ __launch_bounds__(256) void l2norm_kernel(float* __restrict__ mixed) {
  const int r = blockIdx.x * 4 + (threadIdx.x >> 6);
  const int lane = threadIdx.x & 63;
  const int t = r >> 5;
  const int hh = r & 31;
  float* p = mixed + (size_t)t * CQKV + hh * 128 + lane * 2;
  float2 v = *(float2*)p;
  float s = v.x * v.x + v.y * v.y;
#pragma unroll
  for (int off = 32; off > 0; off >>= 1) s += __shfl_down(s, off);
  s = __shfl(s, 0);
  const float rn = rsqrtf(s + 1e-6f);
  v.x *= rn; v.y *= rn;
  *(float2*)p = v;
}

// ---------------- beta, g ----------------
__global__ __launch_bounds__(256) void beta_g_kernel(const float* __restrict__ ba,
                                                     const float* __restrict__ A_log,
                                                     const float* __restrict__ dt_bias,
                                                     const float* __restrict__ mask,
                                                     float* __restrict__ beta,
                                                     float* __restrict__ g) {
  const int idx = blockIdx.x * 256 + threadIdx.x;
  const int t = idx >> 4;
  const int h = idx & 15;
  const float b = ba[(size_t)t * 32 + h];
  const float a = ba[(size_t)t * 32 + 16 + h];
  const float m = mask[t];
  beta[idx] = m / (1.0f + expf(-b));
  const float xx = a + dt_bias[h];
  const float sp = (xx > 20.0f) ? xx : log1pf(expf(xx));
  g[idx] = -expf(A_log[h]) * sp * m;
}

// ---------------- per-chunk cumsum of g + decay factors ----------------
__global__ __launch_bounds__(256) void gcs_kernel(const float* __restrict__ g,
                                                  float* __restrict__ gcsbuf,
                                                  float* __restrict__ edkbuf,
                                                  float* __restrict__ egqbuf,
                                                  float* __restrict__ adecbuf) {
  const int idx = blockIdx.x * 256 + threadIdx.x;  // chunk id = h*64 + n
  if (idx >= 1024) return;
  const int h = idx >> 6;
  const int n = idx & 63;
  const int t0 = n * 64;
  float s = 0.f;
  for (int i = 0; i < 64; i++) {
    s += g[(size_t)(t0 + i) * NH + h];
    gcsbuf[(size_t)idx * 64 + i] = s;
  }
  const float glast = s;
  adecbuf[idx] = __expf(glast);
  for (int i = 0; i < 64; i++) {
    const float gi = gcsbuf[(size_t)idx * 64 + i];
    edkbuf[(size_t)idx * 64 + i] = __expf(glast - gi);
    egqbuf[(size_t)idx * 64 + i] = __expf(gi) * SCALE;
  }
}

// ---------------- per-chunk: A=(k_beta k^T)*decay (strict lower), attn=(q k^T)*decay*scale ----------------
__global__ __launch_bounds__(256) void pre_attn_kernel(const float* __restrict__ mixed,
                                                       const float* __restrict__ gcsbuf,
                                                       const float* __restrict__ betabuf,
                                                       float* __restrict__ abuf,
                                                       float* __restrict__ attnbuf) {
  __shared__ __align__(16) float kl[64][132];
  __shared__ float gcs_s[64];
  __shared__ float betal[64];
  const int blk = blockIdx.x;
  const int h = blk >> 6;
  const int n = blk & 63;
  const int t0 = n * 64;
  const int tid = threadIdx.x;
  if (tid < 64) {
    gcs_s[tid] = gcsbuf[(size_t)blk * 64 + tid];
    betal[tid] = betabuf[(size_t)(t0 + tid) * NH + h];
  }
#pragma unroll
  for (int rep = 0; rep < 8; rep++) {
    const int lin = rep * 256 + tid;
    const int i = lin >> 5;
    const int d = (lin & 31) * 4;
    const float4 kv = *(const float4*)(mixed + (size_t)(t0 + i) * CQKV + 2048 + h * 128 + d);
    *(float4*)&kl[i][d] = kv;
  }
  __syncthreads();
  const int cj = tid & 15;
  const int ri = tid >> 4;
  const int i0 = ri * 4, j0 = cj * 4;
  float accA[4][4], accQ[4][4];
#pragma unroll
  for (int a = 0; a < 4; a++)
#pragma unroll
    for (int b = 0; b < 4; b++) { accA[a][b] = 0.f; accQ[a][b] = 0.f; }
  const float* qbase = mixed + (size_t)t0 * CQKV + h * 128;
#pragma unroll 4
  for (int d = 0; d < 128; d++) {
    const float kj0 = kl[j0][d], kj1 = kl[j0 + 1][d], kj2 = kl[j0 + 2][d], kj3 = kl[j0 + 3][d];
#pragma unroll
    for (int a = 0; a < 4; a++) {
      const float ka = kl[i0 + a][d];
      const float qa = qbase[(size_t)(i0 + a) * CQKV + d];
      accA[a][0] += ka * kj0; accA[a][1] += ka * kj1; accA[a][2] += ka * kj2; accA[a][3] += ka * kj3;
      accQ[a][0] += qa * kj0; accQ[a][1] += qa * kj1; accQ[a][2] += qa * kj2; accQ[a][3] += qa * kj3;
    }
  }
#pragma unroll
  for (int a = 0; a < 4; a++) {
    const int i = i0 + a;
    const float gi = gcs_s[i];
    const float bi = betal[i];
    float4 Av, Qv;
    float dec;
    dec = __expf(fminf(gi - gcs_s[j0 + 0], 0.f));
    Av.x = (i > j0 + 0) ? accA[a][0] * bi * dec : 0.f;
    Qv.x = (i >= j0 + 0) ? accQ[a][0] * dec * SCALE : 0.f;
    dec = __expf(fminf(gi - gcs_s[j0 + 1], 0.f));
    Av.y = (i > j0 + 1) ? accA[a][1] * bi * dec : 0.f;
    Qv.y = (i >= j0 + 1) ? accQ[a][1] * dec * SCALE : 0.f;
    dec = __expf(fminf(gi - gcs_s[j0 + 2], 0.f));
    Av.z = (i > j0 + 2) ? accA[a][2] * bi * dec : 0.f;
    Qv.z = (i >= j0 + 2) ? accQ[a][2] * dec * SCALE : 0.f;
    dec = __expf(fminf(gi - gcs_s[j0 + 3], 0.f));
    Av.w = (i > j0 + 3) ? accA[a][3] * bi * dec : 0.f;
    Qv.w = (i >= j0 + 3) ? accQ[a][3] * dec * SCALE : 0.f;
    *(float4*)(abuf + (size_t)blk * 4096 + i * 64 + j0) = Av;
    *(float4*)(attnbuf + (size_t)blk * 4096 + i * 64 + j0) = Qv;
  }
}

// ---------------- per-chunk: T = (I+A)^-1, then T *= beta[col] ----------------
__global__ __launch_bounds__(256) void pre_solve_kernel(const float* __restrict__ abuf,
                                                        const float* __restrict__ betabuf,
                                                        float* __restrict__ tbuf) {
  __shared__ float Al[64][65];
  __shared__ float Tl[64][65];
  const int blk = blockIdx.x;
  const int h = blk >> 6;
  const int n = blk & 63;
  const int t0 = n * 64;
  const int tid = threadIdx.x;
#pragma unroll
  for (int rep = 0; rep < 4; rep++) {
    const int lin = rep * 256 + tid;
    const int i = lin >> 4;
    const int j = (lin & 15) * 4;
    const float4 av = *(const float4*)(abuf + (size_t)blk * 4096 + i * 64 + j);
    Al[i][j] = av.x; Al[i][j + 1] = av.y; Al[i][j + 2] = av.z; Al[i][j + 3] = av.w;
  }
  __syncthreads();
  if (tid < 64) {
    const int j = tid;
    const float bj = betabuf[(size_t)(t0 + j) * NH + h];
    for (int i = 0; i < 64; i++) {
      float s = (i == j) ? 1.0f : 0.0f;
      for (int l = j; l < i; l++) s -= Al[i][l] * Tl[l][j];
      Tl[i][j] = s;
    }
    for (int i = j; i < 64; i++) Tl[i][j] *= bj;
  }
  __syncthreads();
#pragma unroll
  for (int rep = 0; rep < 4; rep++) {
    const int lin = rep * 256 + tid;
    const int i = lin >> 4;
    const int j = (lin & 15) * 4;
    float4 tv;
    tv.x = Tl[i][j]; tv.y = Tl[i][j + 1]; tv.z = Tl[i][j + 2]; tv.w = Tl[i][j + 3];
    *(float4*)(tbuf + (size_t)blk * 4096 + i * 64 + j) = tv;
  }
}

// ---------------- per-chunk: u = Tb @ v (f32) ; w = Tb @ (k * e^gcs) (bf16) ----------------
__global__ __launch_bounds__(256) void pre_uw_kernel(const float* __restrict__ mixed,
                                                     const float* __restrict__ tbuf,
                                                     const float* __restrict__ gcsbuf,
                                                     float* __restrict__ ubuf,
                                                     unsigned short* __restrict__ wbf) {
  __shared__ __align__(16) float Tl[64][68];
  __shared__ __align__(16) float xl[64][132];
  __shared__ float egcs[64];
  const int blk = blockIdx.x;
  const int h = blk >> 6;
  const int n = blk & 63;
  const int t0 = n * 64;
  const int tid = threadIdx.x;
  if (tid < 64) egcs[tid] = __expf(gcsbuf[(size_t)blk * 64 + tid]);
#pragma unroll
  for (int rep = 0; rep < 4; rep++) {
    const int lin = rep * 256 + tid;
    const int i = lin >> 4;
    const int j = (lin & 15) * 4;
    const float4 tv = *(const float4*)(tbuf + (size_t)blk * 4096 + i * 64 + j);
    *(float4*)&Tl[i][j] = tv;
  }
#pragma unroll
  for (int rep = 0; rep < 8; rep++) {
    const int lin = rep * 256 + tid;
    const int i = lin >> 5;
    const int d = (lin & 31) * 4;
    const float4 vv = *(const float4*)(mixed + (size_t)(t0 + i) * CQKV + 4096 + h * 128 + d);
    *(float4*)&xl[i][d] = vv;
  }
  __syncthreads();
  const int cgu = tid & 15;
  const int riu = tid >> 4;
  const int i0 = riu * 4;
  const int d0 = cgu * 8;
  float acc[4][8];
#pragma unroll
  for (int a = 0; a < 4; a++)
#pragma unroll
    for (int b = 0; b < 8; b++) acc[a][b] = 0.f;
#pragma unroll 2
  for (int j = 0; j < 64; j++) {
    const float tv[4] = {Tl[i0][j], Tl[i0 + 1][j], Tl[i0 + 2][j], Tl[i0 + 3][j]};
    const float4 x0 = *(const float4*)&xl[j][d0];
    const float4 x1 = *(const float4*)&xl[j][d0 + 4];
    const float xv[8] = {x0.x, x0.y, x0.z, x0.w, x1.x, x1.y, x1.z, x1.w};
#pragma unroll
    for (int a = 0; a < 4; a++)
#pragma unroll
      for (int b = 0; b < 8; b++) acc[a][b] += tv[a] * xv[b];
  }
#pragma unroll
  for (int a = 0; a < 4; a++) {
    float* up = ubuf + (size_t)(t0 + i0 + a) * 2048 + h * 128 + d0;
    *(float4*)up = make_float4(acc[a][0], acc[a][1], acc[a][2], acc[a][3]);
    *(float4*)(up + 4) = make_float4(acc[a][4], acc[a][5], acc[a][6], acc[a][7]);
  }
  __syncthreads();
#pragma unroll
  for (int rep = 0; rep < 8; rep++) {
    const int lin = rep * 256 + tid;
    const int i = lin >> 5;
    const int d = (lin & 31) * 4;
    float4 kv = *(const float4*)(mixed + (size_t)(t0 + i) * CQKV + 2048 + h * 128 + d);
    const float e = egcs[i];
    kv.x *= e; kv.y *= e; kv.z *= e; kv.w *= e;
    *(float4*)&xl[i][d] = kv;
  }
  __syncthreads();
#pragma unroll
  for (int a = 0; a < 4; a++)
#pragma unroll
    for (int b = 0; b < 8; b++) acc[a][b] = 0.f;
#pragma unroll 2
  for (int j = 0; j < 64; j++) {
    const float tv[4] = {Tl[i0][j], Tl[i0 + 1][j], Tl[i0 + 2][j], Tl[i0 + 3][j]};
    const float4 x0 = *(const float4*)&xl[j][d0];
    const float4 x1 = *(const float4*)&xl[j][d0 + 4];
    const float xv[8] = {x0.x, x0.y, x0.z, x0.w, x1.x, x1.y, x1.z, x1.w};
#pragma unroll
    for (int a = 0; a < 4; a++)
#pragma unroll
      for (int b = 0; b < 8; b++) acc[a][b] += tv[a] * xv[b];
  }
#pragma unroll
  for (int a = 0; a < 4; a++) {
    unsigned short* wp = wbf + (size_t)(t0 + i0 + a) * 2048 + h * 128 + d0;
    *(ushort4*)wp = pack4(acc[a][0], acc[a][1], acc[a][2], acc[a][3]);
    *(ushort4*)(wp + 4) = pack4(acc[a][4], acc[a][5], acc[a][6], acc[a][7]);
  }
}

// ---------------- per-chunk: kdT[blk][d][l] = bf16( k[t0+l][d] * edk[blk][l] ) ----------------
__global__ __launch_bounds__(256) void ktrans_kernel(const float* __restrict__ mixed,
                                                     const float* __restrict__ edkbuf,
                                                     unsigned short* __restrict__ kdT) {
  __shared__ __align__(16) float kl[64][132];
  __shared__ float edk_s[64];
  const int blk = blockIdx.x;
  const int h = blk >> 6;
  const int n = blk & 63;
  const int t0 = n * 64;
  const int tid = threadIdx.x;
  if (tid < 64) edk_s[tid] = edkbuf[(size_t)blk * 64 + tid];
#pragma unroll
  for (int q = 0; q < 8; q++) {
    const int idx = tid + q * 256;
    const int l = idx >> 5, c4 = (idx & 31) * 4;
    *(float4*)&kl[l][c4] = *(const float4*)(mixed + (size_t)(t0 + l) * CQKV + 2048 + h * 128 + c4);
  }
  __syncthreads();
#pragma unroll
  for (int q = 0; q < 4; q++) {
    const int idx = tid + q * 256;
    const int d = idx >> 3, l8 = (idx & 7) * 8;
    float v[8];
#pragma unroll
    for (int j = 0; j < 8; j++) v[j] = kl[l8 + j][d] * edk_s[l8 + j];
    unsigned short* p = kdT + (size_t)blk * 8192 + d * 64 + l8;
    *(ushort4*)p = pack4(v[0], v[1], v[2], v[3]);
    *(ushort4*)(p + 4) = pack4(v[4], v[5], v[6], v[7]);
  }
}

// ---------------- MFMA sequential scan: 1 block = 1 head, 8 waves, S^T held in accumulators ----------------
// per chunk n: ST_out[blk] = S_n^T (bf16);  vt_out[blk] = v_new^T (bf16);  S_{n+1} = a*S_n + kdec^T @ v_new
// state accum layout: acc2[ct] = C[m = d-tile wv][n = c-tile ct] fragments of S[d][c].
__global__ __launch_bounds__(512) void scan_kernel(const unsigned short* __restrict__ wbf,
                                                   const unsigned short* __restrict__ kdT,
                                                   const float* __restrict__ ubuf,
                                                   const float* __restrict__ adecbuf,
                                                   unsigned short* __restrict__ STb,
                                                   unsigned short* __restrict__ vtb) {
  __shared__ __align__(16) unsigned short w_lds[64 * 128];   // [l][d] bf16, xor-swizzled
  __shared__ __align__(16) unsigned short kT_lds[128 * 64];  // [d][l] bf16, xor-swizzled
  __shared__ __align__(16) unsigned short st_lds[128 * 128]; // [c][d] bf16, xor-swizzled
  __shared__ __align__(16) unsigned short vt_lds[128 * 64];  // [c][l] bf16, xor-swizzled
  __shared__ __align__(16) float u_lds[64 * 132];            // [l][c] f32 (pad 132)
  const int h = blockIdx.x;
  const int tid = threadIdx.x;
  const int ln = tid & 63;
  const int wv = tid >> 6;   // 0..7
  const int fr = ln & 15;
  const int g = ln >> 4;     // 0..3
  const int lt = wv & 3;     // phase-B l-tile
  const int ch = wv >> 2;    // phase-B c-half
  const f32x4 zero = {0.f, 0.f, 0.f, 0.f};

  uint4 wreg[2], kreg[2];
  float4 ureg[4];
  // prefetch chunk 0
#pragma unroll
  for (int q = 0; q < 2; q++) {
    const int idx = tid + q * 512;
    const int row = idx >> 4, c8 = (idx & 15) * 8;
    wreg[q] = *(const uint4*)(wbf + (size_t)row * 2048 + h * 128 + c8);
    const int d = idx >> 3, l8 = (idx & 7) * 8;
    kreg[q] = *(const uint4*)(kdT + (size_t)(h * 64) * 8192 + d * 64 + l8);
  }
#pragma unroll
  for (int q = 0; q < 4; q++) {
    const int idx = tid + q * 512;
    const int row = idx >> 5, c4 = (idx & 31) * 4;
    ureg[q] = *(const float4*)(ubuf + (size_t)row * 2048 + h * 128 + c4);
  }

  f32x4 acc2[8];
#pragma unroll
  for (int ct = 0; ct < 8; ct++) acc2[ct] = zero;

  for (int n = 0; n < 64; n++) {
    const int blk = h * 64 + n;
    // ---- step 1: stage w,u for chunk n; dump S_n^T -> st_lds ----
#pragma unroll
    for (int q = 0; q < 2; q++) {
      const int idx = tid + q * 512;
      const int row = idx >> 4, c8 = (idx & 15) * 8;
      *(uint4*)&w_lds[row * 128 + (((c8 >> 3) ^ (row & 7)) << 3)] = wreg[q];
    }
#pragma unroll
    for (int q = 0; q < 4; q++) {
      const int idx = tid + q * 512;
      const int row = idx >> 5, c4 = (idx & 31) * 4;
      *(float4*)&u_lds[row * 132 + c4] = ureg[q];
    }
    {
      const int db = wv * 16 + g * 4;
#pragma unroll
      for (int ct = 0; ct < 8; ct++) {
        const int c = ct * 16 + fr;
        *(ushort4*)&st_lds[c * 128 + (((db >> 3) ^ (c & 7)) << 3) + (db & 7)] =
            pack4(acc2[ct][0], acc2[ct][1], acc2[ct][2], acc2[ct][3]);
      }
    }
    __syncthreads();  // (A)
    // ---- step 2: stage kT; prefetch n+1; export S_n; v_new = u - w@S ----
#pragma unroll
    for (int q = 0; q < 2; q++) {
      const int idx = tid + q * 512;
      const int d = idx >> 3, l8 = (idx & 7) * 8;
      *(uint4*)&kT_lds[d * 64 + (((l8 >> 3) ^ (d & 7)) << 3)] = kreg[q];
    }
    if (n < 63) {
      const int t0n = (n + 1) * 64;
#pragma unroll
      for (int q = 0; q < 2; q++) {
        const int idx = tid + q * 512;
        const int row = idx >> 4, c8 = (idx & 15) * 8;
        wreg[q] = *(const uint4*)(wbf + (size_t)(t0n + row) * 2048 + h * 128 + c8);
        const int d = idx >> 3, l8 = (idx & 7) * 8;
        kreg[q] = *(const uint4*)(kdT + (size_t)(blk + 1) * 8192 + d * 64 + l8);
      }
#pragma unroll
      for (int q = 0; q < 4; q++) {
        const int idx = tid + q * 512;
        const int row = idx >> 5, c4 = (idx & 31) * 4;
        ureg[q] = *(const float4*)(ubuf + (size_t)(t0n + row) * 2048 + h * 128 + c4);
      }
    }
#pragma unroll
    for (int q = 0; q < 4; q++) {  // S_n^T -> global (unswizzle)
      const int idx = tid + q * 512;
      const int c = idx >> 4, dg = idx & 15;
      *(uint4*)(STb + (size_t)blk * 16384 + c * 128 + dg * 8) =
          *(const uint4*)&st_lds[c * 128 + ((dg ^ (c & 7)) << 3)];
    }
    f32x4 acc1[4];
#pragma unroll
    for (int ct = 0; ct < 4; ct++) acc1[ct] = zero;
#pragma unroll
    for (int ks = 0; ks < 4; ks++) {
      const int kb = ks * 4 + g;
      const int ar = lt * 16 + fr;
      const bf16x8 a = *(const bf16x8*)&w_lds[ar * 128 + ((kb ^ (ar & 7)) << 3)];
#pragma unroll
      for (int ct = 0; ct < 4; ct++) {
        const int c = (ch * 4 + ct) * 16 + fr;
        const bf16x8 b = *(const bf16x8*)&st_lds[c * 128 + ((kb ^ (c & 7)) << 3)];
        acc1[ct] = __builtin_amdgcn_mfma_f32_16x16x32_bf16(a, b, acc1[ct], 0, 0, 0);
      }
    }
    {
      const int lb = lt * 16 + g * 4;
#pragma unroll
      for (int ct = 0; ct < 4; ct++) {
        const int c = (ch * 4 + ct) * 16 + fr;
        const float v0 = u_lds[(lb + 0) * 132 + c] - acc1[ct][0];
        const float v1 = u_lds[(lb + 1) * 132 + c] - acc1[ct][1];
        const float v2 = u_lds[(lb + 2) * 132 + c] - acc1[ct][2];
        const float v3 = u_lds[(lb + 3) * 132 + c] - acc1[ct][3];
        *(ushort4*)&vt_lds[c * 64 + (((lb >> 3) ^ (c & 7)) << 3) + (lb & 7)] =
            pack4(v0, v1, v2, v3);
      }
    }
    const float adec = adecbuf[blk];
    __syncthreads();  // (B)
    // ---- step 3: export v_new^T; S = a*S + kdec^T @ v_new ----
#pragma unroll
    for (int q = 0; q < 2; q++) {
      const int idx = tid + q * 512;
      const int c = idx >> 3, lg = idx & 7;
      *(uint4*)(vtb + (size_t)blk * 8192 + c * 64 + lg * 8) =
          *(const uint4*)&vt_lds[c * 64 + ((lg ^ (c & 7)) << 3)];
    }
#pragma unroll
    for (int ct = 0; ct < 8; ct++) {
      acc2[ct][0] *= adec; acc2[ct][1] *= adec; acc2[ct][2] *= adec; acc2[ct][3] *= adec;
    }
#pragma unroll
    for (int ks = 0; ks < 2; ks++) {
      const int kb = ks * 4 + g;
      const int ar = wv * 16 + fr;
      const bf16x8 a = *(const bf16x8*)&kT_lds[ar * 64 + ((kb ^ (ar & 7)) << 3)];
#pragma unroll
      for (int ct = 0; ct < 8; ct++) {
        const int c = ct * 16 + fr;
        const bf16x8 b = *(const bf16x8*)&vt_lds[c * 64 + ((kb ^ (c & 7)) << 3)];
        acc2[ct] = __builtin_amdgcn_mfma_f32_16x16x32_bf16(a, b, acc2[ct], 0, 0, 0);
      }
    }
  }
}

// ---------------- MFMA o-compute + fused gated RMSNorm ----------------
// o[i][c] = sum_d q̂[i][d]*ST[c][d] + sum_l attn[i][l]*vt[c][l]
// ob[i][c] = bf16( o * rsqrt(mean_c(o^2)+eps) * w[c] * silu(z) )
__global__ __launch_bounds__(256) void ocomp_kernel(const float* __restrict__ mixed,
                                                    const unsigned short* __restrict__ STbuf,
                                                    const unsigned short* __restrict__ vtbuf,
                                                    const float* __restrict__ attnbuf,
                                                    const float* __restrict__ egqbuf,
                                                    const unsigned short* __restrict__ zb,
                                                    const float* __restrict__ onw,
                                                    unsigned short* __restrict__ ob) {
  __shared__ __align__(16) unsigned short STl[128 * 128];  // [c][d]
  __shared__ __align__(16) unsigned short vtl[128 * 64];   // [c][l]
  __shared__ __align__(16) unsigned short ql[64 * 128];    // [i][d]
  __shared__ __align__(16) unsigned short al[64 * 64];     // [i][l]
  const int blk = blockIdx.x;
  const int h = blk >> 6;
  const int n = blk & 63;
  const int t0 = n * 64;
  const int tid = threadIdx.x;
#pragma unroll
  for (int q = 0; q < 8; q++) {
    const int idx = tid + q * 256;
    const int c = idx >> 4, dg = idx & 15;
    *(uint4*)&STl[c * 128 + ((dg ^ (c & 7)) << 3)] =
        *(const uint4*)(STbuf + (size_t)blk * 16384 + c * 128 + dg * 8);
  }
#pragma unroll
  for (int q = 0; q < 4; q++) {
    const int idx = tid + q * 256;
    const int c = idx >> 3, lg = idx & 7;
    *(uint4*)&vtl[c * 64 + ((lg ^ (c & 7)) << 3)] =
        *(const uint4*)(vtbuf + (size_t)blk * 8192 + c * 64 + lg * 8);
  }
#pragma unroll
  for (int q = 0; q < 8; q++) {
    const int idx = tid + q * 256;
    const int i = idx >> 5, c4 = (idx & 31) * 4;
    const float eg = egqbuf[(size_t)blk * 64 + i];
    const float4 v = *(const float4*)(mixed + (size_t)(t0 + i) * CQKV + h * 128 + c4);
    *(ushort4*)&ql[i * 128 + (((c4 >> 3) ^ (i & 7)) << 3) + (c4 & 7)] =
        pack4(v.x * eg, v.y * eg, v.z * eg, v.w * eg);
  }
#pragma unroll
  for (int q = 0; q < 4; q++) {
    const int idx = tid + q * 256;
    const int i = idx >> 4, l4 = (idx & 15) * 4;
    const float4 v = *(const float4*)(attnbuf + (size_t)blk * 4096 + i * 64 + l4);
    *(ushort4*)&al[i * 64 + (((l4 >> 3) ^ (i & 7)) << 3) + (l4 & 7)] =
        pack4(v.x, v.y, v.z, v.w);
  }
  __syncthreads();
  const int ln = tid & 63;
  const int wv = tid >> 6;
  const int fr = ln & 15;
  const int g = ln >> 4;
  const int i0 = wv * 16;
  f32x4 acc[8];
  const f32x4 zero = {0.f, 0.f, 0.f, 0.f};
#pragma unroll
  for (int nt = 0; nt < 8; nt++) acc[nt] = zero;
#pragma unroll
  for (int ks = 0; ks < 4; ks++) {
    const int kb = ks * 4 + g;
    const int ar = i0 + fr;
    const bf16x8 a = *(const bf16x8*)&ql[ar * 128 + ((kb ^ (ar & 7)) << 3)];
#pragma unroll
    for (int nt = 0; nt < 8; nt++) {
      const int c = nt * 16 + fr;
      const bf16x8 b = *(const bf16x8*)&STl[c * 128 + ((kb ^ (c & 7)) << 3)];
      acc[nt] = __builtin_amdgcn_mfma_f32_16x16x32_bf16(a, b, acc[nt], 0, 0, 0);
    }
  }
#pragma unroll
  for (int ks = 0; ks < 2; ks++) {
    const int kb = ks * 4 + g;
    const int ar = i0 + fr;
    const bf16x8 a = *(const bf16x8*)&al[ar * 64 + ((kb ^ (ar & 7)) << 3)];
#pragma unroll
    for (int nt = 0; nt < 8; nt++) {
      const int c = nt * 16 + fr;
      const bf16x8 b = *(const bf16x8*)&vtl[c * 64 + ((kb ^ (c & 7)) << 3)];
      acc[nt] = __builtin_amdgcn_mfma_f32_16x16x32_bf16(a, b, acc[nt], 0, 0, 0);
    }
  }
  // fused gated RMSNorm: rows i = i0 + g*4 + r ; cols c = fr + 16*nt
  float s0 = 0.f, s1 = 0.f, s2 = 0.f, s3 = 0.f;
#pragma unroll
  for (int nt = 0; nt < 8; nt++) {
    s0 += acc[nt][0] * acc[nt][0];
    s1 += acc[nt][1] * acc[nt][1];
    s2 += acc[nt][2] * acc[nt][2];
    s3 += acc[nt][3] * acc[nt][3];
  }
#pragma unroll
  for (int m = 1; m < 16; m <<= 1) {
    s0 += __shfl_xor(s0, m);
    s1 += __shfl_xor(s1, m);
    s2 += __shfl_xor(s2, m);
    s3 += __shfl_xor(s3, m);
  }
  float rn[4];
  rn[0] = rsqrtf(s0 * (1.0f / 128.0f) + 1e-5f);
  rn[1] = rsqrtf(s1 * (1.0f / 128.0f) + 1e-5f);
  rn[2] = rsqrtf(s2 * (1.0f / 128.0f) + 1e-5f);
  rn[3] = rsqrtf(s3 * (1.0f / 128.0f) + 1e-5f);
#pragma unroll
  for (int nt = 0; nt < 8; nt++) {
    const int c = nt * 16 + fr;
    const float wn = onw[c];
#pragma unroll
    for (int r = 0; r < 4; r++) {
      const size_t off = (size_t)(t0 + i0 + g * 4 + r) * 2048 + h * 128 + c;
      const float zz = siluf(bf2f(zb[off]));
      ob[off] = f2bf(acc[nt][r] * rn[r] * wn * zz);
    }
  }
}

// ---------------- helpers ----------------
__global__ __launch_bounds__(256) void copy_kernel(const float* __restrict__ in,
                                                   float* __restrict__ out) {
  const int i = blockIdx.x * 256 + threadIdx.x;
  ((float4*)out)[i] = ((const float4*)in)[i];
}

extern "C" void kernel_launch(void* const* d_in, const int* in_sizes, int n_in,
                              void* d_out, int out_size, void* d_ws, size_t ws_size,
                              hipStream_t stream) {
  (void)in_sizes; (void)n_in; (void)out_size;
  const float* x        = (const float*)d_in[0];
  const float* mask     = (const float*)d_in[1];
  const float* ln1_w    = (const float*)d_in[2];
  const float* qkvz_w   = (const float*)d_in[3];
  const float* ba_w     = (const float*)d_in[4];
  const float* conv_w   = (const float*)d_in[5];
  const float* A_log    = (const float*)d_in[6];
  const float* dt_bias  = (const float*)d_in[7];
  const float* o_norm_w = (const float*)d_in[8];
  const float* out_w    = (const float*)d_in[9];
  const float* ln2_w    = (const float*)d_in[10];
  const float* gate_w   = (const float*)d_in[11];
  const float* up_w     = (const float*)d_in[12];
  const float* down_w   = (const float*)d_in[13];
  float* out = (float*)d_out;

  const size_t NEED_BYTES = (size_t)75825152 * 4;
  if (ws_size < NEED_BYTES) return;

  float* ws = (float*)d_ws;
  // [0, 25165824): mixed_f32 (phase A)  ->  Wg/Wu/Wd bf16 (MLP phase)
  float* mixed_buf = ws;
  unsigned short* Wg = (unsigned short*)ws;
  unsigned short* Wu = (unsigned short*)(ws + 8388608);
  unsigned short* Wd = (unsigned short*)(ws + 16777216);
  // [25165824, 41943040): qkvz_bf16 -> u f32 / wbf bf16 / kdT bf16 -> gate/comb bf16
  unsigned short* qkvz_bf = (unsigned short*)(ws + 25165824);
  float* u_buf = ws + 25165824;                              // 8388608 f
  unsigned short* wbf = (unsigned short*)(ws + 33554432);    // 4096x2048 bf16
  unsigned short* kdT = (unsigned short*)(ws + 37748736);    // 1024x128x64 bf16
  unsigned short* gate_bf = (unsigned short*)(ws + 25165824);
  // [41943040, 46137344): z bf16
  unsigned short* z_bf = (unsigned short*)(ws + 41943040);
  // [46137344, 54525952): h_f32 -> a_buf -> vt_buf ; t_buf
  float* h_buf = ws + 46137344;
  float* a_buf = ws + 46137344;
  unsigned short* vt_buf = (unsigned short*)(ws + 46137344); // 1024x128x64 bf16
  float* t_buf = ws + 50331648;
  // [54525952, 58720256): h_bf16 -> ob bf16 -> h2_bf16
  unsigned short* h_bf  = (unsigned short*)(ws + 54525952);
  unsigned short* ob    = (unsigned short*)(ws + 54525952);
  unsigned short* h2_bf = (unsigned short*)(ws + 54525952);
  // [58720256, 62914560): attn f32
  float* attn_buf = ws + 58720256;
  // [62914560, 71303168): Wq bf16 -> STbuf bf16 (1024 x 128 x 128, S^T layout [c][d])
  unsigned short* Wq = (unsigned short*)(ws + 62914560);
  unsigned short* ST_buf = (unsigned short*)(ws + 62914560);
  // [71303168, 73400320): Wo bf16
  unsigned short* Wo = (unsigned short*)(ws + 71303168);
  // smalls
  float* ba_buf   = ws + 73400320;
  float* beta_buf = ws + 73531392;
  float* g_buf    = ws + 73596928;
  float* gcs_buf  = ws + 73662464;
  float* edk_buf  = ws + 73728000;   // [1024][64]
  float* egq_buf  = ws + 73793536;   // [1024][64]
  float* adec_buf = ws + 73859072;   // [1024]

  rmsnorm_kernel<1><<<4096, 256, 0, stream>>>(x, ln1_w, h_buf, h_bf);
  f2b_kernel<<<8192, 256, 0, stream>>>(qkvz_w, Wq);
  gemm_bf16_kernel<0><<<dim3(64, 32), 256, 0, stream>>>(h_bf, Wq, nullptr, qkvz_bf, 4096, 8192, 2048);
  ba_gemm_kernel<<<4096, 256, 0, stream>>>(h_buf, ba_w, ba_buf);
  zcopy_kernel<<<4096, 256, 0, stream>>>(qkvz_bf, z_bf);
  conv_silu_kernel<<<24576, 256, 0, stream>>>(qkvz_bf, conv_w, mask, mixed_buf);
  l2norm_kernel<<<32768, 256, 0, stream>>>(mixed_buf);
  beta_g_kernel<<<256, 256, 0, stream>>>(ba_buf, A_log, dt_bias, mask, beta_buf, g_buf);
  gcs_kernel<<<4, 256, 0, stream>>>(g_buf, gcs_buf, edk_buf, egq_buf, adec_buf);
  pre_attn_kernel<<<1024, 256, 0, stream>>>(mixed_buf, gcs_buf, beta_buf, a_buf, attn_buf);
  pre_solve_kernel<<<1024, 256, 0, stream>>>(a_buf, beta_buf, t_buf);
  pre_uw_kernel<<<1024, 256, 0, stream>>>(mixed_buf, t_buf, gcs_buf, u_buf, wbf);
  ktrans_kernel<<<1024, 256, 0, stream>>>(mixed_buf, edk_buf, kdT);
  // MFMA sequential scan: 16 heads, state in accumulators
  scan_kernel<<<16, 512, 0, stream>>>(wbf, kdT, u_buf, adec_buf, ST_buf, vt_buf);
  // MFMA o computation + fused gated RMSNorm
  ocomp_kernel<<<1024, 256, 0, stream>>>(mixed_buf, ST_buf, vt_buf, attn_buf, egq_buf,
                                         z_bf, o_norm_w, ob);
  // weight converts for the back half (mixed now dead)
  f2b_kernel<<<8192, 256, 0, stream>>>(gate_w, Wg);
  f2b_kernel<<<8192, 256, 0, stream>>>(up_w, Wu);
  f2b_kernel<<<8192, 256, 0, stream>>>(down_w, Wd);
  f2b_kernel<<<2048, 256, 0, stream>>>(out_w, Wo);
  copy_kernel<<<8192, 256, 0, stream>>>(x, out);
  gemm_bf16_kernel<1><<<dim3(16, 32), 256, 0, stream>>>(ob, Wo, out, nullptr, 4096, 2048, 2048);
  rmsnorm_kernel<2><<<4096, 256, 0, stream>>>(out, ln2_w, nullptr, h2_bf);
  gemm_bf16_kernel<0><<<dim3(64, 32), 256, 0, stream>>>(h2_bf, Wg, nullptr, gate_bf, 4096, 8192, 2048);
  gemm_bf16_kernel<2><<<dim3(64, 32), 256, 0, stream>>>(h2_bf, Wu, nullptr, gate_bf, 4096, 8192, 2048);
  gemm_bf16_kernel<1><<<dim3(16, 32), 256, 0, stream>>>(gate_bf, Wd, out, nullptr, 4096, 2048, 8192);
}

// Round 3
// 1583.135 us; speedup vs baseline: 1.2479x; 1.1159x over previous
//
#include <hip/hip_runtime.h>
#include <math.h>

#define T_LEN 4096
#define DMODEL 2048
#define NH 16
#define CQKV 6144
#define CQKVZ 8192
#define SCALE 0.08838834764831845f   // 128^-0.5

using bf16x8 = __attribute__((ext_vector_type(8))) short;
using f32x4  = __attribute__((ext_vector_type(4))) float;

__device__ __forceinline__ float siluf(float x) { return x / (1.0f + __expf(-x)); }

__device__ __forceinline__ unsigned short f2bf(float f) {  // RNE
  unsigned int u = __float_as_uint(f);
  u = (u + 0x7FFFu + ((u >> 16) & 1u)) >> 16;
  return (unsigned short)u;
}
__device__ __forceinline__ float bf2f(unsigned short u) {
  return __uint_as_float(((unsigned int)u) << 16);
}
__device__ __forceinline__ ushort4 pack4(float a, float b, float c, float d) {
  ushort4 r; r.x = f2bf(a); r.y = f2bf(b); r.z = f2bf(c); r.w = f2bf(d); return r;
}

// async global->LDS, 16 bytes per lane; LDS dest is wave-uniform base (+ lane*16 implicit)
__device__ __forceinline__ void gl_lds16(const unsigned short* g, unsigned short* l) {
  __builtin_amdgcn_global_load_lds(
      (const __attribute__((address_space(1))) void*)g,
      (__attribute__((address_space(3))) void*)l, 16, 0, 0);
}

// ---------------- RMSNorm over D=2048; MODE: 1 = f32+bf16, 2 = bf16 only ----------------
template<int MODE>
__global__ __launch_bounds__(256) void rmsnorm_kernel(const float* __restrict__ x,
                                                      const float* __restrict__ w,
                                                      float* __restrict__ outf,
                                                      unsigned short* __restrict__ outb) {
  const int t = blockIdx.x;
  const int tid = threadIdx.x;
  const float4* xr = (const float4*)(x + (size_t)t * DMODEL);
  float4 v0 = xr[tid];
  float4 v1 = xr[tid + 256];
  float s = v0.x*v0.x + v0.y*v0.y + v0.z*v0.z + v0.w*v0.w
          + v1.x*v1.x + v1.y*v1.y + v1.z*v1.z + v1.w*v1.w;
#pragma unroll
  for (int off = 32; off > 0; off >>= 1) s += __shfl_down(s, off);
  __shared__ float red[4];
  if ((tid & 63) == 0) red[tid >> 6] = s;
  __syncthreads();
  const float tot = red[0] + red[1] + red[2] + red[3];
  const float r = rsqrtf(tot * (1.0f / DMODEL) + 1e-5f);
  const float4* wr = (const float4*)w;
  const float4 w0 = wr[tid], w1 = wr[tid + 256];
  float4 o0, o1;
  o0.x = v0.x*r*w0.x; o0.y = v0.y*r*w0.y; o0.z = v0.z*r*w0.z; o0.w = v0.w*r*w0.w;
  o1.x = v1.x*r*w1.x; o1.y = v1.y*r*w1.y; o1.z = v1.z*r*w1.z; o1.w = v1.w*r*w1.w;
  if (MODE == 1) {
    float4* orow = (float4*)(outf + (size_t)t * DMODEL);
    orow[tid] = o0;
    orow[tid + 256] = o1;
  }
  ushort4* brow = (ushort4*)(outb + (size_t)t * DMODEL);
  brow[tid] = pack4(o0.x, o0.y, o0.z, o0.w);
  brow[tid + 256] = pack4(o1.x, o1.y, o1.z, o1.w);
}

// ---------------- fp32 -> bf16 bulk convert ----------------
__global__ __launch_bounds__(256) void f2b_kernel(const float* __restrict__ in,
                                                  unsigned short* __restrict__ out) {
  const size_t i = (size_t)blockIdx.x * 256 + threadIdx.x;
  const float4 a = ((const float4*)in)[2 * i];
  const float4 b = ((const float4*)in)[2 * i + 1];
  ((ushort4*)out)[2 * i] = pack4(a.x, a.y, a.z, a.w);
  ((ushort4*)out)[2 * i + 1] = pack4(b.x, b.y, b.z, b.w);
}

// ---------------- 256x256 pipelined bf16 MFMA GEMM: C[M][N] = A[M][K] * B[N][K]^T -------------
// 8 waves (2M x 4N), BK=64, double-buffered 128KiB LDS, counted vmcnt(8) pipeline (never drains
// in steady state), T2 XOR-swizzle via pre-swizzled global source + swizzled ds_read.
// EPI: 0 = bf16 store, 1 = fp32 accumulate, 2 = silu(gate)*acc -> bf16 in place
template<int EPI>
__global__ __launch_bounds__(512, 2) void gemm256_kernel(const unsigned short* __restrict__ A,
                                                         const unsigned short* __restrict__ B,
                                                         float* __restrict__ Cf,
                                                         unsigned short* __restrict__ Cb,
                                                         int M, int N, int K) {
  __shared__ __align__(16) unsigned short lds[2][2][16384];  // [buf][A/B][256*64]
  const int nbm = M >> 8, nbn = N >> 8, nwg = nbm * nbn;
  const int nt = K >> 6;
  // 2D XCD-chunked bijective block swizzle
  int bmi, bni;
  {
    const int bid = blockIdx.x;
    const int cpx = nwg >> 3;
    int sc = 1;
    while (sc * sc < cpx) sc <<= 1;
    if (sc * sc > cpx) sc >>= 1;
    const int scn = (sc > 0) ? (cpx / sc) : 0;
    if ((nwg & 7) == 0 && sc > 0 && sc * scn == cpx && (nbm % sc) == 0 && (nbn % scn) == 0) {
      const int chunk = bid & 7, widx = bid >> 3;
      const int regc = nbn / scn;
      bmi = (chunk / regc) * sc + widx / scn;
      bni = (chunk % regc) * scn + widx % scn;
    } else {
      bmi = bid / nbn; bni = bid % nbn;
    }
  }
  const int bm = bmi << 8, bn = bni << 8;
  const int tid = threadIdx.x;
  const int wv = tid >> 6, ln = tid & 63;
  const int fr = ln & 15, qq = ln >> 4;
  const int wm = wv >> 2, wn = wv & 3;
  // staging: instruction q covers rows q*64 + wv*8 + (ln>>3); source col slot inverse-swizzled
  const int srow = wv * 8 + (ln >> 3);
  const int scol = ((ln & 7) ^ (ln >> 3)) << 3;
  const unsigned short* Ag = A + (size_t)(bm + srow) * K + scol;
  const unsigned short* Bg = B + (size_t)(bn + srow) * K + scol;
  const size_t gq = (size_t)64 * K;

  f32x4 acc[8][4];
  const f32x4 zero = {0.f, 0.f, 0.f, 0.f};
#pragma unroll
  for (int mi = 0; mi < 8; mi++)
#pragma unroll
    for (int ni = 0; ni < 4; ni++) acc[mi][ni] = zero;

  auto stage = [&](int buf, int t) {
    const int k0 = t << 6;
    unsigned short* la = &lds[buf][0][wv * 512];
    unsigned short* lb = &lds[buf][1][wv * 512];
#pragma unroll
    for (int q = 0; q < 4; q++) {
      gl_lds16(Ag + q * gq + k0, la + q * 4096);
      gl_lds16(Bg + q * gq + k0, lb + q * 4096);
    }
  };

  // prologue: tiles 0,1 in flight; wait tile0 (8 newest stay outstanding)
  stage(0, 0);
  stage(1, 1);
  asm volatile("s_waitcnt vmcnt(8)" ::: "memory");
  __builtin_amdgcn_s_barrier();
  asm volatile("" ::: "memory");

  const int ra0 = wm * 128, rb0 = wn * 64;
  for (int t = 0; t < nt; t++) {
    const unsigned short* la = &lds[t & 1][0][0];
    const unsigned short* lb = &lds[t & 1][1][0];
    bf16x8 bfr[2][4];
#pragma unroll
    for (int ks = 0; ks < 2; ks++)
#pragma unroll
      for (int ni = 0; ni < 4; ni++) {
        const int r = rb0 + ni * 16 + fr;
        bfr[ks][ni] = *(const bf16x8*)&lb[r * 64 + (((ks * 4 + qq) ^ (r & 7)) << 3)];
      }
#pragma unroll
    for (int ks = 0; ks < 2; ks++)
#pragma unroll
      for (int mi = 0; mi < 8; mi++) {
        const int r = ra0 + mi * 16 + fr;
        const bf16x8 a = *(const bf16x8*)&la[r * 64 + (((ks * 4 + qq) ^ (r & 7)) << 3)];
#pragma unroll
        for (int ni = 0; ni < 4; ni++)
          acc[mi][ni] = __builtin_amdgcn_mfma_f32_16x16x32_bf16(a, bfr[ks][ni], acc[mi][ni], 0, 0, 0);
      }
    __builtin_amdgcn_s_barrier();      // all waves done reading buf[t&1]
    asm volatile("" ::: "memory");
    if (t + 2 < nt) {
      stage(t & 1, t + 2);             // refill freed buffer
      asm volatile("s_waitcnt vmcnt(8)" ::: "memory");   // tile t+1 landed; t+2 in flight
    } else {
      asm volatile("s_waitcnt vmcnt(0)" ::: "memory");   // tail drain
    }
    __builtin_amdgcn_s_barrier();      // next buffer published to all waves
    asm volatile("" ::: "memory");
  }

  const int cm4 = qq * 4;
#pragma unroll
  for (int mi = 0; mi < 8; mi++) {
#pragma unroll
    for (int ni = 0; ni < 4; ni++) {
#pragma unroll
      for (int r = 0; r < 4; r++) {
        const int grow = bm + ra0 + mi * 16 + cm4 + r;
        const int gcol = bn + rb0 + ni * 16 + fr;
        const size_t off = (size_t)grow * N + gcol;
        const float v = acc[mi][ni][r];
        if (EPI == 0) {
          Cb[off] = f2bf(v);
        } else if (EPI == 1) {
          Cf[off] += v;
        } else {
          Cb[off] = f2bf(siluf(bf2f(Cb[off])) * v);
        }
      }
    }
  }
}

// ---------------- ba = h @ ba_w^T ----------------
__global__ __launch_bounds__(256) void ba_gemm_kernel(const float* __restrict__ h_in,
                                                      const float* __restrict__ ba_w,
                                                      float* __restrict__ ba_out) {
  __shared__ __align__(16) float hl[2048];
  __shared__ float red[32][9];
  const int t = blockIdx.x;
  const int tid = threadIdx.x;
  const float4* hr = (const float4*)(h_in + (size_t)t * DMODEL);
  ((float4*)hl)[tid] = hr[tid];
  ((float4*)hl)[tid + 256] = hr[tid + 256];
  __syncthreads();
  const int c = tid & 31;
  const int p = tid >> 5;
  const float* wrow = ba_w + (size_t)c * DMODEL + p * 256;
  const float* hrow = hl + p * 256;
  float s = 0.f;
#pragma unroll 8
  for (int k = 0; k < 256; k++) s += hrow[k] * wrow[k];
  red[c][p] = s;
  __syncthreads();
  if (tid < 32) {
    float tot = 0.f;
#pragma unroll
    for (int q = 0; q < 8; q++) tot += red[tid][q];
    ba_out[(size_t)t * 32 + tid] = tot;
  }
}

// ---------------- extract z columns from bf16 qkvz ----------------
__global__ __launch_bounds__(256) void zcopy_kernel(const unsigned short* __restrict__ qkvz,
                                                    unsigned short* __restrict__ z) {
  const int idx = blockIdx.x * 256 + threadIdx.x;
  const int t = idx >> 8;
  const int c8 = (idx & 255) * 8;
  *(uint4*)(z + (size_t)t * 2048 + c8) =
      *(const uint4*)(qkvz + (size_t)t * CQKVZ + CQKV + c8);
}

// ---------------- causal depthwise conv (K=4) + SiLU; bf16 in, fp32 out ----------------
__global__ __launch_bounds__(256) void conv_silu_kernel(const unsigned short* __restrict__ qkvz,
                                                        const float* __restrict__ conv_w,
                                                        const float* __restrict__ mask,
                                                        float* __restrict__ mixed) {
  const int idx = blockIdx.x * 256 + threadIdx.x;
  const int c4 = (idx % 1536) * 4;
  const int t = idx / 1536;
  const float4 w0 = *(const float4*)(conv_w + (size_t)c4 * 4);
  const float4 w1 = *(const float4*)(conv_w + (size_t)c4 * 4 + 4);
  const float4 w2 = *(const float4*)(conv_w + (size_t)c4 * 4 + 8);
  const float4 w3 = *(const float4*)(conv_w + (size_t)c4 * 4 + 12);
  const float wj0[4] = {w0.x, w0.y, w0.z, w0.w};
  const float wj1[4] = {w1.x, w1.y, w1.z, w1.w};
  const float wj2[4] = {w2.x, w2.y, w2.z, w2.w};
  const float wj3[4] = {w3.x, w3.y, w3.z, w3.w};
  float4 acc = make_float4(0.f, 0.f, 0.f, 0.f);
#pragma unroll
  for (int j = 0; j < 4; j++) {
    const int tt = t - 3 + j;
    if (tt < 0) continue;
    const float m = mask[tt];
    const ushort4 xb = *(const ushort4*)(qkvz + (size_t)tt * CQKVZ + c4);
    acc.x += bf2f(xb.x) * m * wj0[j];
    acc.y += bf2f(xb.y) * m * wj1[j];
    acc.z += bf2f(xb.z) * m * wj2[j];
    acc.w += bf2f(xb.w) * m * wj3[j];
  }
  acc.x = siluf(acc.x); acc.y = siluf(acc.y); acc.z = siluf(acc.z); acc.w = siluf(acc.w);
  *(float4*)(mixed + (size_t)t * CQKV + c4) = acc;
}

// ---------------- l2norm over Dk=128 for q,k heads (in place, fp32) ----------------
__global__ __launch_bounds__(256) void l2norm_kernel(float* __restrict__ mixed) {
  const int r = blockIdx.x * 4 + (threadIdx.x >> 6);
  const int lane = threadIdx.x & 63;
  const int t = r >> 5;
  const int hh = r & 31;
  float* p = mixed + (size_t)t * CQKV + hh * 128 + lane * 2;
  float2 v = *(float2*)p;
  float s = v.x * v.x + v.y * v.y;
#pragma unroll
  for (int off = 32; off > 0; off >>= 1) s += __shfl_down(s, off);
  s = __shfl(s, 0);
  const float rn = rsqrtf(s + 1e-6f);
  v.x *= rn; v.y *= rn;
  *(float2*)p = v;
}

// ---------------- beta, g ----------------
__global__ __launch_bounds__(256) void beta_g_kernel(const float* __restrict__ ba,
                                                     const float* __restrict__ A_log,
                                                     const float* __restrict__ dt_bias,
                                                     const float* __restrict__ mask,
                                                     float* __restrict__ beta,
                                                     float* __restrict__ g) {
  const int idx = blockIdx.x * 256 + threadIdx.x;
  const int t = idx >> 4;
  const int h = idx & 15;
  const float b = ba[(size_t)t * 32 + h];
  const float a = ba[(size_t)t * 32 + 16 + h];
  const float m = mask[t];
  beta[idx] = m / (1.0f + expf(-b));
  const float xx = a + dt_bias[h];
  const float sp = (xx > 20.0f) ? xx : log1pf(expf(xx));
  g[idx] = -expf(A_log[h]) * sp * m;
}

// ---------------- per-chunk cumsum of g + decay factors ----------------
__global__ __launch_bounds__(256) void gcs_kernel(const float* __restrict__ g,
                                                  float* __restrict__ gcsbuf,
                                                  float* __restrict__ edkbuf,
                                                  float* __restrict__ egqbuf,
                                                  float* __restrict__ adecbuf) {
  const int idx = blockIdx.x * 256 + threadIdx.x;  // chunk id = h*64 + n
  if (idx >= 1024) return;
  const int h = idx >> 6;
  const int n = idx & 63;
  const int t0 = n * 64;
  float s = 0.f;
  for (int i = 0; i < 64; i++) {
    s += g[(size_t)(t0 + i) * NH + h];
    gcsbuf[(size_t)idx * 64 + i] = s;
  }
  const float glast = s;
  adecbuf[idx] = __expf(glast);
  for (int i = 0; i < 64; i++) {
    const float gi = gcsbuf[(size_t)idx * 64 + i];
    edkbuf[(size_t)idx * 64 + i] = __expf(glast - gi);
    egqbuf[(size_t)idx * 64 + i] = __expf(gi) * SCALE;
  }
}

// ---------------- per-chunk: A=(k_beta k^T)*decay (strict lower), attn=(q k^T)*decay*scale ----------------
__global__ __launch_bounds__(256) void pre_attn_kernel(const float* __restrict__ mixed,
                                                       const float* __restrict__ gcsbuf,
                                                       const float* __restrict__ betabuf,
                                                       float* __restrict__ abuf,
                                                       float* __restrict__ attnbuf) {
  __shared__ __align__(16) float kl[64][132];
  __shared__ float gcs_s[64];
  __shared__ float betal[64];
  const int blk = blockIdx.x;
  const int h = blk >> 6;
  const int n = blk & 63;
  const int t0 = n * 64;
  const int tid = threadIdx.x;
  if (tid < 64) {
    gcs_s[tid] = gcsbuf[(size_t)blk * 64 + tid];
    betal[tid] = betabuf[(size_t)(t0 + tid) * NH + h];
  }
#pragma unroll
  for (int rep = 0; rep < 8; rep++) {
    const int lin = rep * 256 + tid;
    const int i = lin >> 5;
    const int d = (lin & 31) * 4;
    const float4 kv = *(const float4*)(mixed + (size_t)(t0 + i) * CQKV + 2048 + h * 128 + d);
    *(float4*)&kl[i][d] = kv;
  }
  __syncthreads();
  const int cj = tid & 15;
  const int ri = tid >> 4;
  const int i0 = ri * 4, j0 = cj * 4;
  float accA[4][4], accQ[4][4];
#pragma unroll
  for (int a = 0; a < 4; a++)
#pragma unroll
    for (int b = 0; b < 4; b++) { accA[a][b] = 0.f; accQ[a][b] = 0.f; }
  const float* qbase = mixed + (size_t)t0 * CQKV + h * 128;
#pragma unroll 4
  for (int d = 0; d < 128; d++) {
    const float kj0 = kl[j0][d], kj1 = kl[j0 + 1][d], kj2 = kl[j0 + 2][d], kj3 = kl[j0 + 3][d];
#pragma unroll
    for (int a = 0; a < 4; a++) {
      const float ka = kl[i0 + a][d];
      const float qa = qbase[(size_t)(i0 + a) * CQKV + d];
      accA[a][0] += ka * kj0; accA[a][1] += ka * kj1; accA[a][2] += ka * kj2; accA[a][3] += ka * kj3;
      accQ[a][0] += qa * kj0; accQ[a][1] += qa * kj1; accQ[a][2] += qa * kj2; accQ[a][3] += qa * kj3;
    }
  }
#pragma unroll
  for (int a = 0; a < 4; a++) {
    const int i = i0 + a;
    const float gi = gcs_s[i];
    const float bi = betal[i];
    float4 Av, Qv;
    float dec;
    dec = __expf(fminf(gi - gcs_s[j0 + 0], 0.f));
    Av.x = (i > j0 + 0) ? accA[a][0] * bi * dec : 0.f;
    Qv.x = (i >= j0 + 0) ? accQ[a][0] * dec * SCALE : 0.f;
    dec = __expf(fminf(gi - gcs_s[j0 + 1], 0.f));
    Av.y = (i > j0 + 1) ? accA[a][1] * bi * dec : 0.f;
    Qv.y = (i >= j0 + 1) ? accQ[a][1] * dec * SCALE : 0.f;
    dec = __expf(fminf(gi - gcs_s[j0 + 2], 0.f));
    Av.z = (i > j0 + 2) ? accA[a][2] * bi * dec : 0.f;
    Qv.z = (i >= j0 + 2) ? accQ[a][2] * dec * SCALE : 0.f;
    dec = __expf(fminf(gi - gcs_s[j0 + 3], 0.f));
    Av.w = (i > j0 + 3) ? accA[a][3] * bi * dec : 0.f;
    Qv.w = (i >= j0 + 3) ? accQ[a][3] * dec * SCALE : 0.f;
    *(float4*)(abuf + (size_t)blk * 4096 + i * 64 + j0) = Av;
    *(float4*)(attnbuf + (size_t)blk * 4096 + i * 64 + j0) = Qv;
  }
}

// ---------------- per-chunk: T = (I+A)^-1, then T *= beta[col] ----------------
__global__ __launch_bounds__(256) void pre_solve_kernel(const float* __restrict__ abuf,
                                                        const float* __restrict__ betabuf,
                                                        float* __restrict__ tbuf) {
  __shared__ float Al[64][65];
  __shared__ float Tl[64][65];
  const int blk = blockIdx.x;
  const int h = blk >> 6;
  const int n = blk & 63;
  const int t0 = n * 64;
  const int tid = threadIdx.x;
#pragma unroll
  for (int rep = 0; rep < 4; rep++) {
    const int lin = rep * 256 + tid;
    const int i = lin >> 4;
    const int j = (lin & 15) * 4;
    const float4 av = *(const float4*)(abuf + (size_t)blk * 4096 + i * 64 + j);
    Al[i][j] = av.x; Al[i][j + 1] = av.y; Al[i][j + 2] = av.z; Al[i][j + 3] = av.w;
  }
  __syncthreads();
  if (tid < 64) {
    const int j = tid;
    const float bj = betabuf[(size_t)(t0 + j) * NH + h];
    for (int i = 0; i < 64; i++) {
      float s = (i == j) ? 1.0f : 0.0f;
      for (int l = j; l < i; l++) s -= Al[i][l] * Tl[l][j];
      Tl[i][j] = s;
    }
    for (int i = j; i < 64; i++) Tl[i][j] *= bj;
  }
  __syncthreads();
#pragma unroll
  for (int rep = 0; rep < 4; rep++) {
    const int lin = rep * 256 + tid;
    const int i = lin >> 4;
    const int j = (lin & 15) * 4;
    float4 tv;
    tv.x = Tl[i][j]; tv.y = Tl[i][j + 1]; tv.z = Tl[i][j + 2]; tv.w = Tl[i][j + 3];
    *(float4*)(tbuf + (size_t)blk * 4096 + i * 64 + j) = tv;
  }
}

// ---------------- per-chunk: u = Tb @ v (f32) ; w = Tb @ (k * e^gcs) (bf16) ----------------
__global__ __launch_bounds__(256) void pre_uw_kernel(const float* __restrict__ mixed,
                                                     const float* __restrict__ tbuf,
                                                     const float* __restrict__ gcsbuf,
                                                     float* __restrict__ ubuf,
                                                     unsigned short* __restrict__ wbf) {
  __shared__ __align__(16) float Tl[64][68];
  __shared__ __align__(16) float xl[64][132];
  __shared__ float egcs[64];
  const int blk = blockIdx.x;
  const int h = blk >> 6;
  const int n = blk & 63;
  const int t0 = n * 64;
  const int tid = threadIdx.x;
  if (tid < 64) egcs[tid] = __expf(gcsbuf[(size_t)blk * 64 + tid]);
#pragma unroll
  for (int rep = 0; rep < 4; rep++) {
    const int lin = rep * 256 + tid;
    const int i = lin >> 4;
    const int j = (lin & 15) * 4;
    const float4 tv = *(const float4*)(tbuf + (size_t)blk * 4096 + i * 64 + j);
    *(float4*)&Tl[i][j] = tv;
  }
#pragma unroll
  for (int rep = 0; rep < 8; rep++) {
    const int lin = rep * 256 + tid;
    const int i = lin >> 5;
    const int d = (lin & 31) * 4;
    const float4 vv = *(const float4*)(mixed + (size_t)(t0 + i) * CQKV + 4096 + h * 128 + d);
    *(float4*)&xl[i][d] = vv;
  }
  __syncthreads();
  const int cgu = tid & 15;
  const int riu = tid >> 4;
  const int i0 = riu * 4;
  const int d0 = cgu * 8;
  float acc[4][8];
#pragma unroll
  for (int a = 0; a < 4; a++)
#pragma unroll
    for (int b = 0; b < 8; b++) acc[a][b] = 0.f;
#pragma unroll 2
  for (int j = 0; j < 64; j++) {
    const float tv[4] = {Tl[i0][j], Tl[i0 + 1][j], Tl[i0 + 2][j], Tl[i0 + 3][j]};
    const float4 x0 = *(const float4*)&xl[j][d0];
    const float4 x1 = *(const float4*)&xl[j][d0 + 4];
    const float xv[8] = {x0.x, x0.y, x0.z, x0.w, x1.x, x1.y, x1.z, x1.w};
#pragma unroll
    for (int a = 0; a < 4; a++)
#pragma unroll
      for (int b = 0; b < 8; b++) acc[a][b] += tv[a] * xv[b];
  }
#pragma unroll
  for (int a = 0; a < 4; a++) {
    float* up = ubuf + (size_t)(t0 + i0 + a) * 2048 + h * 128 + d0;
    *(float4*)up = make_float4(acc[a][0], acc[a][1], acc[a][2], acc[a][3]);
    *(float4*)(up + 4) = make_float4(acc[a][4], acc[a][5], acc[a][6], acc[a][7]);
  }
  __syncthreads();
#pragma unroll
  for (int rep = 0; rep < 8; rep++) {
    const int lin = rep * 256 + tid;
    const int i = lin >> 5;
    const int d = (lin & 31) * 4;
    float4 kv = *(const float4*)(mixed + (size_t)(t0 + i) * CQKV + 2048 + h * 128 + d);
    const float e = egcs[i];
    kv.x *= e; kv.y *= e; kv.z *= e; kv.w *= e;
    *(float4*)&xl[i][d] = kv;
  }
  __syncthreads();
#pragma unroll
  for (int a = 0; a < 4; a++)
#pragma unroll
    for (int b = 0; b < 8; b++) acc[a][b] = 0.f;
#pragma unroll 2
  for (int j = 0; j < 64; j++) {
    const float tv[4] = {Tl[i0][j], Tl[i0 + 1][j], Tl[i0 + 2][j], Tl[i0 + 3][j]};
    const float4 x0 = *(const float4*)&xl[j][d0];
    const float4 x1 = *(const float4*)&xl[j][d0 + 4];
    const float xv[8] = {x0.x, x0.y, x0.z, x0.w, x1.x, x1.y, x1.z, x1.w};
#pragma unroll
    for (int a = 0; a < 4; a++)
#pragma unroll
      for (int b = 0; b < 8; b++) acc[a][b] += tv[a] * xv[b];
  }
#pragma unroll
  for (int a = 0; a < 4; a++) {
    unsigned short* wp = wbf + (size_t)(t0 + i0 + a) * 2048 + h * 128 + d0;
    *(ushort4*)wp = pack4(acc[a][0], acc[a][1], acc[a][2], acc[a][3]);
    *(ushort4*)(wp + 4) = pack4(acc[a][4], acc[a][5], acc[a][6], acc[a][7]);
  }
}

// ---------------- per-chunk: kdT[blk][d][l] = bf16( k[t0+l][d] * edk[blk][l] ) ----------------
__global__ __launch_bounds__(256) void ktrans_kernel(const float* __restrict__ mixed,
                                                     const float* __restrict__ edkbuf,
                                                     unsigned short* __restrict__ kdT) {
  __shared__ __align__(16) float kl[64][132];
  __shared__ float edk_s[64];
  const int blk = blockIdx.x;
  const int h = blk >> 6;
  const int n = blk & 63;
  const int t0 = n * 64;
  const int tid = threadIdx.x;
  if (tid < 64) edk_s[tid] = edkbuf[(size_t)blk * 64 + tid];
#pragma unroll
  for (int q = 0; q < 8; q++) {
    const int idx = tid + q * 256;
    const int l = idx >> 5, c4 = (idx & 31) * 4;
    *(float4*)&kl[l][c4] = *(const float4*)(mixed + (size_t)(t0 + l) * CQKV + 2048 + h * 128 + c4);
  }
  __syncthreads();
#pragma unroll
  for (int q = 0; q < 4; q++) {
    const int idx = tid + q * 256;
    const int d = idx >> 3, l8 = (idx & 7) * 8;
    float v[8];
#pragma unroll
    for (int j = 0; j < 8; j++) v[j] = kl[l8 + j][d] * edk_s[l8 + j];
    unsigned short* p = kdT + (size_t)blk * 8192 + d * 64 + l8;
    *(ushort4*)p = pack4(v[0], v[1], v[2], v[3]);
    *(ushort4*)(p + 4) = pack4(v[4], v[5], v[6], v[7]);
  }
}

// ---------------- MFMA sequential scan: 1 block = 1 head, 8 waves, S^T held in accumulators ----------------
__global__ __launch_bounds__(512) void scan_kernel(const unsigned short* __restrict__ wbf,
                                                   const unsigned short* __restrict__ kdT,
                                                   const float* __restrict__ ubuf,
                                                   const float* __restrict__ adecbuf,
                                                   unsigned short* __restrict__ STb,
                                                   unsigned short* __restrict__ vtb) {
  __shared__ __align__(16) unsigned short w_lds[64 * 128];   // [l][d] bf16, xor-swizzled
  __shared__ __align__(16) unsigned short kT_lds[128 * 64];  // [d][l] bf16, xor-swizzled
  __shared__ __align__(16) unsigned short st_lds[128 * 128]; // [c][d] bf16, xor-swizzled
  __shared__ __align__(16) unsigned short vt_lds[128 * 64];  // [c][l] bf16, xor-swizzled
  __shared__ __align__(16) float u_lds[64 * 132];            // [l][c] f32 (pad 132)
  const int h = blockIdx.x;
  const int tid = threadIdx.x;
  const int ln = tid & 63;
  const int wv = tid >> 6;   // 0..7
  const int fr = ln & 15;
  const int g = ln >> 4;     // 0..3
  const int lt = wv & 3;     // phase-B l-tile
  const int ch = wv >> 2;    // phase-B c-half
  const f32x4 zero = {0.f, 0.f, 0.f, 0.f};

  uint4 wreg[2], kreg[2];
  float4 ureg[4];
  // prefetch chunk 0
#pragma unroll
  for (int q = 0; q < 2; q++) {
    const int idx = tid + q * 512;
    const int row = idx >> 4, c8 = (idx & 15) * 8;
    wreg[q] = *(const uint4*)(wbf + (size_t)row * 2048 + h * 128 + c8);
    const int d = idx >> 3, l8 = (idx & 7) * 8;
    kreg[q] = *(const uint4*)(kdT + (size_t)(h * 64) * 8192 + d * 64 + l8);
  }
#pragma unroll
  for (int q = 0; q < 4; q++) {
    const int idx = tid + q * 512;
    const int row = idx >> 5, c4 = (idx & 31) * 4;
    ureg[q] = *(const float4*)(ubuf + (size_t)row * 2048 + h * 128 + c4);
  }

  f32x4 acc2[8];
#pragma unroll
  for (int ct = 0; ct < 8; ct++) acc2[ct] = zero;

  for (int n = 0; n < 64; n++) {
    const int blk = h * 64 + n;
    // ---- step 1: stage w,u for chunk n; dump S_n^T -> st_lds ----
#pragma unroll
    for (int q = 0; q < 2; q++) {
      const int idx = tid + q * 512;
      const int row = idx >> 4, c8 = (idx & 15) * 8;
      *(uint4*)&w_lds[row * 128 + (((c8 >> 3) ^ (row & 7)) << 3)] = wreg[q];
    }
#pragma unroll
    for (int q = 0; q < 4; q++) {
      const int idx = tid + q * 512;
      const int row = idx >> 5, c4 = (idx & 31) * 4;
      *(float4*)&u_lds[row * 132 + c4] = ureg[q];
    }
    {
      const int db = wv * 16 + g * 4;
#pragma unroll
      for (int ct = 0; ct < 8; ct++) {
        const int c = ct * 16 + fr;
        *(ushort4*)&st_lds[c * 128 + (((db >> 3) ^ (c & 7)) << 3) + (db & 7)] =
            pack4(acc2[ct][0], acc2[ct][1], acc2[ct][2], acc2[ct][3]);
      }
    }
    __syncthreads();  // (A)
    // ---- step 2: stage kT; prefetch n+1; export S_n; v_new = u - w@S ----
#pragma unroll
    for (int q = 0; q < 2; q++) {
      const int idx = tid + q * 512;
      const int d = idx >> 3, l8 = (idx & 7) * 8;
      *(uint4*)&kT_lds[d * 64 + (((l8 >> 3) ^ (d & 7)) << 3)] = kreg[q];
    }
    if (n < 63) {
      const int t0n = (n + 1) * 64;
#pragma unroll
      for (int q = 0; q < 2; q++) {
        const int idx = tid + q * 512;
        const int row = idx >> 4, c8 = (idx & 15) * 8;
        wreg[q] = *(const uint4*)(wbf + (size_t)(t0n + row) * 2048 + h * 128 + c8);
        const int d = idx >> 3, l8 = (idx & 7) * 8;
        kreg[q] = *(const uint4*)(kdT + (size_t)(blk + 1) * 8192 + d * 64 + l8);
      }
#pragma unroll
      for (int q = 0; q < 4; q++) {
        const int idx = tid + q * 512;
        const int row = idx >> 5, c4 = (idx & 31) * 4;
        ureg[q] = *(const float4*)(ubuf + (size_t)(t0n + row) * 2048 + h * 128 + c4);
      }
    }
#pragma unroll
    for (int q = 0; q < 4; q++) {  // S_n^T -> global (unswizzle)
      const int idx = tid + q * 512;
      const int c = idx >> 4, dg = idx & 15;
      *(uint4*)(STb + (size_t)blk * 16384 + c * 128 + dg * 8) =
          *(const uint4*)&st_lds[c * 128 + ((dg ^ (c & 7)) << 3)];
    }
    f32x4 acc1[4];
#pragma unroll
    for (int ct = 0; ct < 4; ct++) acc1[ct] = zero;
#pragma unroll
    for (int ks = 0; ks < 4; ks++) {
      const int kb = ks * 4 + g;
      const int ar = lt * 16 + fr;
      const bf16x8 a = *(const bf16x8*)&w_lds[ar * 128 + ((kb ^ (ar & 7)) << 3)];
#pragma unroll
      for (int ct = 0; ct < 4; ct++) {
        const int c = (ch * 4 + ct) * 16 + fr;
        const bf16x8 b = *(const bf16x8*)&st_lds[c * 128 + ((kb ^ (c & 7)) << 3)];
        acc1[ct] = __builtin_amdgcn_mfma_f32_16x16x32_bf16(a, b, acc1[ct], 0, 0, 0);
      }
    }
    {
      const int lb = lt * 16 + g * 4;
#pragma unroll
      for (int ct = 0; ct < 4; ct++) {
        const int c = (ch * 4 + ct) * 16 + fr;
        const float v0 = u_lds[(lb + 0) * 132 + c] - acc1[ct][0];
        const float v1 = u_lds[(lb + 1) * 132 + c] - acc1[ct][1];
        const float v2 = u_lds[(lb + 2) * 132 + c] - acc1[ct][2];
        const float v3 = u_lds[(lb + 3) * 132 + c] - acc1[ct][3];
        *(ushort4*)&vt_lds[c * 64 + (((lb >> 3) ^ (c & 7)) << 3) + (lb & 7)] =
            pack4(v0, v1, v2, v3);
      }
    }
    const float adec = adecbuf[blk];
    __syncthreads();  // (B)
    // ---- step 3: export v_new^T; S = a*S + kdec^T @ v_new ----
#pragma unroll
    for (int q = 0; q < 2; q++) {
      const int idx = tid + q * 512;
      const int c = idx >> 3, lg = idx & 7;
      *(uint4*)(vtb + (size_t)blk * 8192 + c * 64 + lg * 8) =
          *(const uint4*)&vt_lds[c * 64 + ((lg ^ (c & 7)) << 3)];
    }
#pragma unroll
    for (int ct = 0; ct < 8; ct++) {
      acc2[ct][0] *= adec; acc2[ct][1] *= adec; acc2[ct][2] *= adec; acc2[ct][3] *= adec;
    }
#pragma unroll
    for (int ks = 0; ks < 2; ks++) {
      const int kb = ks * 4 + g;
      const int ar = wv * 16 + fr;
      const bf16x8 a = *(const bf16x8*)&kT_lds[ar * 64 + ((kb ^ (ar & 7)) << 3)];
#pragma unroll
      for (int ct = 0; ct < 8; ct++) {
        const int c = ct * 16 + fr;
        const bf16x8 b = *(const bf16x8*)&vt_lds[c * 64 + ((kb ^ (c & 7)) << 3)];
        acc2[ct] = __builtin_amdgcn_mfma_f32_16x16x32_bf16(a, b, acc2[ct], 0, 0, 0);
      }
    }
  }
}

// ---------------- MFMA o-compute + fused gated RMSNorm ----------------
__global__ __launch_bounds__(256) void ocomp_kernel(const float* __restrict__ mixed,
                                                    const unsigned short* __restrict__ STbuf,
                                                    const unsigned short* __restrict__ vtbuf,
                                                    const float* __restrict__ attnbuf,
                                                    const float* __restrict__ egqbuf,
                                                    const unsigned short* __restrict__ zb,
                                                    const float* __restrict__ onw,
                                                    unsigned short* __restrict__ ob) {
  __shared__ __align__(16) unsigned short STl[128 * 128];  // [c][d]
  __shared__ __align__(16) unsigned short vtl[128 * 64];   // [c][l]
  __shared__ __align__(16) unsigned short ql[64 * 128];    // [i][d]
  __shared__ __align__(16) unsigned short al[64 * 64];     // [i][l]
  const int blk = blockIdx.x;
  const int h = blk >> 6;
  const int n = blk & 63;
  const int t0 = n * 64;
  const int tid = threadIdx.x;
#pragma unroll
  for (int q = 0; q < 8; q++) {
    const int idx = tid + q * 256;
    const int c = idx >> 4, dg = idx & 15;
    *(uint4*)&STl[c * 128 + ((dg ^ (c & 7)) << 3)] =
        *(const uint4*)(STbuf + (size_t)blk * 16384 + c * 128 + dg * 8);
  }
#pragma unroll
  for (int q = 0; q < 4; q++) {
    const int idx = tid + q * 256;
    const int c = idx >> 3, lg = idx & 7;
    *(uint4*)&vtl[c * 64 + ((lg ^ (c & 7)) << 3)] =
        *(const uint4*)(vtbuf + (size_t)blk * 8192 + c * 64 + lg * 8);
  }
#pragma unroll
  for (int q = 0; q < 8; q++) {
    const int idx = tid + q * 256;
    const int i = idx >> 5, c4 = (idx & 31) * 4;
    const float eg = egqbuf[(size_t)blk * 64 + i];
    const float4 v = *(const float4*)(mixed + (size_t)(t0 + i) * CQKV + h * 128 + c4);
    *(ushort4*)&ql[i * 128 + (((c4 >> 3) ^ (i & 7)) << 3) + (c4 & 7)] =
        pack4(v.x * eg, v.y * eg, v.z * eg, v.w * eg);
  }
#pragma unroll
  for (int q = 0; q < 4; q++) {
    const int idx = tid + q * 256;
    const int i = idx >> 4, l4 = (idx & 15) * 4;
    const float4 v = *(const float4*)(attnbuf + (size_t)blk * 4096 + i * 64 + l4);
    *(ushort4*)&al[i * 64 + (((l4 >> 3) ^ (i & 7)) << 3) + (l4 & 7)] =
        pack4(v.x, v.y, v.z, v.w);
  }
  __syncthreads();
  const int ln = tid & 63;
  const int wv = tid >> 6;
  const int fr = ln & 15;
  const int g = ln >> 4;
  const int i0 = wv * 16;
  f32x4 acc[8];
  const f32x4 zero = {0.f, 0.f, 0.f, 0.f};
#pragma unroll
  for (int nt = 0; nt < 8; nt++) acc[nt] = zero;
#pragma unroll
  for (int ks = 0; ks < 4; ks++) {
    const int kb = ks * 4 + g;
    const int ar = i0 + fr;
    const bf16x8 a = *(const bf16x8*)&ql[ar * 128 + ((kb ^ (ar & 7)) << 3)];
#pragma unroll
    for (int nt = 0; nt < 8; nt++) {
      const int c = nt * 16 + fr;
      const bf16x8 b = *(const bf16x8*)&STl[c * 128 + ((kb ^ (c & 7)) << 3)];
      acc[nt] = __builtin_amdgcn_mfma_f32_16x16x32_bf16(a, b, acc[nt], 0, 0, 0);
    }
  }
#pragma unroll
  for (int ks = 0; ks < 2; ks++) {
    const int kb = ks * 4 + g;
    const int ar = i0 + fr;
    const bf16x8 a = *(const bf16x8*)&al[ar * 64 + ((kb ^ (ar & 7)) << 3)];
#pragma unroll
    for (int nt = 0; nt < 8; nt++) {
      const int c = nt * 16 + fr;
      const bf16x8 b = *(const bf16x8*)&vtl[c * 64 + ((kb ^ (c & 7)) << 3)];
      acc[nt] = __builtin_amdgcn_mfma_f32_16x16x32_bf16(a, b, acc[nt], 0, 0, 0);
    }
  }
  float s0 = 0.f, s1 = 0.f, s2 = 0.f, s3 = 0.f;
#pragma unroll
  for (int nt = 0; nt < 8; nt++) {
    s0 += acc[nt][0] * acc[nt][0];
    s1 += acc[nt][1] * acc[nt][1];
    s2 += acc[nt][2] * acc[nt][2];
    s3 += acc[nt][3] * acc[nt][3];
  }
#pragma unroll
  for (int m = 1; m < 16; m <<= 1) {
    s0 += __shfl_xor(s0, m);
    s1 += __shfl_xor(s1, m);
    s2 += __shfl_xor(s2, m);
    s3 += __shfl_xor(s3, m);
  }
  float rn[4];
  rn[0] = rsqrtf(s0 * (1.0f / 128.0f) + 1e-5f);
  rn[1] = rsqrtf(s1 * (1.0f / 128.0f) + 1e-5f);
  rn[2] = rsqrtf(s2 * (1.0f / 128.0f) + 1e-5f);
  rn[3] = rsqrtf(s3 * (1.0f / 128.0f) + 1e-5f);
#pragma unroll
  for (int nt = 0; nt < 8; nt++) {
    const int c = nt * 16 + fr;
    const float wn = onw[c];
#pragma unroll
    for (int r = 0; r < 4; r++) {
      const size_t off = (size_t)(t0 + i0 + g * 4 + r) * 2048 + h * 128 + c;
      const float zz = siluf(bf2f(zb[off]));
      ob[off] = f2bf(acc[nt][r] * rn[r] * wn * zz);
    }
  }
}

// ---------------- helpers ----------------
__global__ __launch_bounds__(256) void copy_kernel(const float* __restrict__ in,
                                                   float* __restrict__ out) {
  const int i = blockIdx.x * 256 + threadIdx.x;
  ((float4*)out)[i] = ((const float4*)in)[i];
}

extern "C" void kernel_launch(void* const* d_in, const int* in_sizes, int n_in,
                              void* d_out, int out_size, void* d_ws, size_t ws_size,
                              hipStream_t stream) {
  (void)in_sizes; (void)n_in; (void)out_size;
  const float* x        = (const float*)d_in[0];
  const float* mask     = (const float*)d_in[1];
  const float* ln1_w    = (const float*)d_in[2];
  const float* qkvz_w   = (const float*)d_in[3];
  const float* ba_w     = (const float*)d_in[4];
  const float* conv_w   = (const float*)d_in[5];
  const float* A_log    = (const float*)d_in[6];
  const float* dt_bias  = (const float*)d_in[7];
  const float* o_norm_w = (const float*)d_in[8];
  const float* out_w    = (const float*)d_in[9];
  const float* ln2_w    = (const float*)d_in[10];
  const float* gate_w   = (const float*)d_in[11];
  const float* up_w     = (const float*)d_in[12];
  const float* down_w   = (const float*)d_in[13];
  float* out = (float*)d_out;

  const size_t NEED_BYTES = (size_t)75825152 * 4;
  if (ws_size < NEED_BYTES) return;

  float* ws = (float*)d_ws;
  float* mixed_buf = ws;
  unsigned short* Wg = (unsigned short*)ws;
  unsigned short* Wu = (unsigned short*)(ws + 8388608);
  unsigned short* Wd = (unsigned short*)(ws + 16777216);
  unsigned short* qkvz_bf = (unsigned short*)(ws + 25165824);
  float* u_buf = ws + 25165824;
  unsigned short* wbf = (unsigned short*)(ws + 33554432);
  unsigned short* kdT = (unsigned short*)(ws + 37748736);
  unsigned short* gate_bf = (unsigned short*)(ws + 25165824);
  unsigned short* z_bf = (unsigned short*)(ws + 41943040);
  float* h_buf = ws + 46137344;
  float* a_buf = ws + 46137344;
  unsigned short* vt_buf = (unsigned short*)(ws + 46137344);
  float* t_buf = ws + 50331648;
  unsigned short* h_bf  = (unsigned short*)(ws + 54525952);
  unsigned short* ob    = (unsigned short*)(ws + 54525952);
  unsigned short* h2_bf = (unsigned short*)(ws + 54525952);
  float* attn_buf = ws + 58720256;
  unsigned short* Wq = (unsigned short*)(ws + 62914560);
  unsigned short* ST_buf = (unsigned short*)(ws + 62914560);
  unsigned short* Wo = (unsigned short*)(ws + 71303168);
  float* ba_buf   = ws + 73400320;
  float* beta_buf = ws + 73531392;
  float* g_buf    = ws + 73596928;
  float* gcs_buf  = ws + 73662464;
  float* edk_buf  = ws + 73728000;
  float* egq_buf  = ws + 73793536;
  float* adec_buf = ws + 73859072;

  rmsnorm_kernel<1><<<4096, 256, 0, stream>>>(x, ln1_w, h_buf, h_bf);
  f2b_kernel<<<8192, 256, 0, stream>>>(qkvz_w, Wq);
  gemm256_kernel<0><<<512, 512, 0, stream>>>(h_bf, Wq, nullptr, qkvz_bf, 4096, 8192, 2048);
  ba_gemm_kernel<<<4096, 256, 0, stream>>>(h_buf, ba_w, ba_buf);
  zcopy_kernel<<<4096, 256, 0, stream>>>(qkvz_bf, z_bf);
  conv_silu_kernel<<<24576, 256, 0, stream>>>(qkvz_bf, conv_w, mask, mixed_buf);
  l2norm_kernel<<<32768, 256, 0, stream>>>(mixed_buf);
  beta_g_kernel<<<256, 256, 0, stream>>>(ba_buf, A_log, dt_bias, mask, beta_buf, g_buf);
  gcs_kernel<<<4, 256, 0, stream>>>(g_buf, gcs_buf, edk_buf, egq_buf, adec_buf);
  pre_attn_kernel<<<1024, 256, 0, stream>>>(mixed_buf, gcs_buf, beta_buf, a_buf, attn_buf);
  pre_solve_kernel<<<1024, 256, 0, stream>>>(a_buf, beta_buf, t_buf);
  pre_uw_kernel<<<1024, 256, 0, stream>>>(mixed_buf, t_buf, gcs_buf, u_buf, wbf);
  ktrans_kernel<<<1024, 256, 0, stream>>>(mixed_buf, edk_buf, kdT);
  scan_kernel<<<16, 512, 0, stream>>>(wbf, kdT, u_buf, adec_buf, ST_buf, vt_buf);
  ocomp_kernel<<<1024, 256, 0, stream>>>(mixed_buf, ST_buf, vt_buf, attn_buf, egq_buf,
                                         z_bf, o_norm_w, ob);
  f2b_kernel<<<8192, 256, 0, stream>>>(gate_w, Wg);
  f2b_kernel<<<8192, 256, 0, stream>>>(up_w, Wu);
  f2b_kernel<<<8192, 256, 0, stream>>>(down_w, Wd);
  f2b_kernel<<<2048, 256, 0, stream>>>(out_w, Wo);
  copy_kernel<<<8192, 256, 0, stream>>>(x, out);
  gemm256_kernel<1><<<128, 512, 0, stream>>>(ob, Wo, out, nullptr, 4096, 2048, 2048);
  rmsnorm_kernel<2><<<4096, 256, 0, stream>>>(out, ln2_w, nullptr, h2_bf);
  gemm256_kernel<0><<<512, 512, 0, stream>>>(h2_bf, Wg, nullptr, gate_bf, 4096, 8192, 2048);
  gemm256_kernel<2><<<512, 512, 0, stream>>>(h2_bf, Wu, nullptr, gate_bf, 4096, 8192, 2048);
  gemm256_kernel<1><<<128, 512, 0, stream>>>(gate_bf, Wd, out, nullptr, 4096, 2048, 8192);
}

// Round 4
// 1479.973 us; speedup vs baseline: 1.3349x; 1.0697x over previous
//
#include <hip/hip_runtime.h>
#include <math.h>

#define T_LEN 4096
#define DMODEL 2048
#define NH 16
#define CQKV 6144
#define CQKVZ 8192
#define SCALE 0.08838834764831845f   // 128^-0.5

using bf16x8 = __attribute__((ext_vector_type(8))) short;
using f32x4  = __attribute__((ext_vector_type(4))) float;

__device__ __forceinline__ float siluf(float x) { return x / (1.0f + __expf(-x)); }

__device__ __forceinline__ unsigned short f2bf(float f) {  // RNE
  unsigned int u = __float_as_uint(f);
  u = (u + 0x7FFFu + ((u >> 16) & 1u)) >> 16;
  return (unsigned short)u;
}
__device__ __forceinline__ float bf2f(unsigned short u) {
  return __uint_as_float(((unsigned int)u) << 16);
}
__device__ __forceinline__ ushort4 pack4(float a, float b, float c, float d) {
  ushort4 r; r.x = f2bf(a); r.y = f2bf(b); r.z = f2bf(c); r.w = f2bf(d); return r;
}

// async global->LDS, 16 bytes per lane; LDS dest is wave-uniform base (+ lane*16 implicit)
__device__ __forceinline__ void gl_lds16(const unsigned short* g, unsigned short* l) {
  __builtin_amdgcn_global_load_lds(
      (const __attribute__((address_space(1))) void*)g,
      (__attribute__((address_space(3))) void*)l, 16, 0, 0);
}

// ---------------- RMSNorm over D=2048; MODE: 1 = f32+bf16, 2 = bf16 only ----------------
template<int MODE>
__global__ __launch_bounds__(256) void rmsnorm_kernel(const float* __restrict__ x,
                                                      const float* __restrict__ w,
                                                      float* __restrict__ outf,
                                                      unsigned short* __restrict__ outb) {
  const int t = blockIdx.x;
  const int tid = threadIdx.x;
  const float4* xr = (const float4*)(x + (size_t)t * DMODEL);
  float4 v0 = xr[tid];
  float4 v1 = xr[tid + 256];
  float s = v0.x*v0.x + v0.y*v0.y + v0.z*v0.z + v0.w*v0.w
          + v1.x*v1.x + v1.y*v1.y + v1.z*v1.z + v1.w*v1.w;
#pragma unroll
  for (int off = 32; off > 0; off >>= 1) s += __shfl_down(s, off);
  __shared__ float red[4];
  if ((tid & 63) == 0) red[tid >> 6] = s;
  __syncthreads();
  const float tot = red[0] + red[1] + red[2] + red[3];
  const float r = rsqrtf(tot * (1.0f / DMODEL) + 1e-5f);
  const float4* wr = (const float4*)w;
  const float4 w0 = wr[tid], w1 = wr[tid + 256];
  float4 o0, o1;
  o0.x = v0.x*r*w0.x; o0.y = v0.y*r*w0.y; o0.z = v0.z*r*w0.z; o0.w = v0.w*r*w0.w;
  o1.x = v1.x*r*w1.x; o1.y = v1.y*r*w1.y; o1.z = v1.z*r*w1.z; o1.w = v1.w*r*w1.w;
  if (MODE == 1) {
    float4* orow = (float4*)(outf + (size_t)t * DMODEL);
    orow[tid] = o0;
    orow[tid + 256] = o1;
  }
  ushort4* brow = (ushort4*)(outb + (size_t)t * DMODEL);
  brow[tid] = pack4(o0.x, o0.y, o0.z, o0.w);
  brow[tid + 256] = pack4(o1.x, o1.y, o1.z, o1.w);
}

// ---------------- fp32 -> bf16 bulk convert ----------------
__global__ __launch_bounds__(256) void f2b_kernel(const float* __restrict__ in,
                                                  unsigned short* __restrict__ out) {
  const size_t i = (size_t)blockIdx.x * 256 + threadIdx.x;
  const float4 a = ((const float4*)in)[2 * i];
  const float4 b = ((const float4*)in)[2 * i + 1];
  ((ushort4*)out)[2 * i] = pack4(a.x, a.y, a.z, a.w);
  ((ushort4*)out)[2 * i + 1] = pack4(b.x, b.y, b.z, b.w);
}

// ---------------- pipelined bf16 MFMA GEMM: C[M][N] = A[M][K] * B[N][K]^T -------------------
// BM x 256 tile, BK=32, 8 waves, 3 LDS buffers: stage tile t+2 during tile t, counted
// vmcnt (never drains in steady state), ONE barrier per K-tile, setprio around MFMA cluster.
// LDS slot swizzle: phys_slot = slot ^ ((row>>1)&3) -> 2-way bank aliasing (free).
// EPI: 0 = bf16 store, 1 = fp32 accumulate, 2 = silu(gate)*acc -> bf16 in place
template<int EPI, int BM>
__global__ __launch_bounds__(512, 1) void gemm256_kernel(const unsigned short* __restrict__ A,
                                                         const unsigned short* __restrict__ B,
                                                         float* __restrict__ Cf,
                                                         unsigned short* __restrict__ Cb,
                                                         int M, int N, int K) {
  constexpr int BN = 256;
  constexpr int MI = BM / 32;        // 8 (BM=256) or 4 (BM=128) m-frags per wave
  constexpr int AW = BM / 128;       // A stage instructions per wave (2 or 1)
  __shared__ __align__(16) unsigned short lds[3][(BM + BN) * 32];
  const int nbm = M / BM, nbn = N / BN, nwg = nbm * nbn;
  const int nt = K >> 5;
  // 2D XCD-chunked bijective block swizzle
  int bmi, bni;
  {
    const int bid = blockIdx.x;
    const int cpx = nwg >> 3;
    int sc = 1;
    while (sc * sc < cpx) sc <<= 1;
    if (sc * sc > cpx) sc >>= 1;
    const int scn = (sc > 0) ? (cpx / sc) : 0;
    if ((nwg & 7) == 0 && sc > 0 && sc * scn == cpx && (nbm % sc) == 0 && (nbn % scn) == 0) {
      const int chunk = bid & 7, widx = bid >> 3;
      const int regc = nbn / scn;
      bmi = (chunk / regc) * sc + widx / scn;
      bni = (chunk % regc) * scn + widx % scn;
    } else {
      bmi = bid / nbn; bni = bid % nbn;
    }
  }
  const int bm = bmi * BM, bn = bni * BN;
  const int tid = threadIdx.x;
  const int wv = tid >> 6, ln = tid & 63;
  const int fr = ln & 15, qq = ln >> 4;
  const int wm = wv >> 2, wn = wv & 3;
  const int ra0 = wm * (BM / 2), rb0 = wn * 64;
  // staging lane map: lane covers (row_local = ln>>2, phys slot = ln&3); source slot inverse-swz
  const int lrow = ln >> 2;
  const int lslot = ln & 3;

  f32x4 acc[MI][4];
  const f32x4 zero = {0.f, 0.f, 0.f, 0.f};
#pragma unroll
  for (int mi = 0; mi < MI; mi++)
#pragma unroll
    for (int ni = 0; ni < 4; ni++) acc[mi][ni] = zero;

  auto stageA = [&](int buf, int t) {
    const int k0 = t << 5;
#pragma unroll
    for (int q = 0; q < AW; q++) {
      const int lr = q * 128 + wv * 16 + lrow;
      const int sl = lslot ^ ((lr >> 1) & 3);
      gl_lds16(A + (size_t)(bm + lr) * K + k0 + sl * 8,
               &lds[buf][(q * 128 + wv * 16) * 32]);
    }
  };
  auto stageB = [&](int buf, int t) {
    const int k0 = t << 5;
#pragma unroll
    for (int q = 0; q < 2; q++) {
      const int lr = q * 128 + wv * 16 + lrow;
      const int sl = lslot ^ ((lr >> 1) & 3);
      gl_lds16(B + (size_t)(bn + lr) * K + k0 + sl * 8,
               &lds[buf][BM * 32 + (q * 128 + wv * 16) * 32]);
    }
  };

  // prologue: tiles 0,1 staged; wait tile0 (tile1's loads stay outstanding)
  stageA(0, 0); stageB(0, 0);
  stageA(1, 1); stageB(1, 1);
  if constexpr (AW == 2) asm volatile("s_waitcnt vmcnt(4)" ::: "memory");
  else                   asm volatile("s_waitcnt vmcnt(3)" ::: "memory");
  __builtin_amdgcn_s_barrier();
  asm volatile("" ::: "memory");

  for (int t = 0; t < nt; t++) {
    const int cb = t % 3;
    const int b2 = (t + 2) % 3;
    const unsigned short* lA = &lds[cb][0];
    const unsigned short* lB = &lds[cb][BM * 32];
    bf16x8 bfr[4];
#pragma unroll
    for (int ni = 0; ni < 4; ni++) {
      const int r = rb0 + ni * 16 + fr;
      bfr[ni] = *(const bf16x8*)&lB[r * 32 + ((qq ^ ((r >> 1) & 3)) << 3)];
    }
    bf16x8 afr[MI];
#pragma unroll
    for (int mi = 0; mi < MI; mi++) {
      const int r = ra0 + mi * 16 + fr;
      afr[mi] = *(const bf16x8*)&lA[r * 32 + ((qq ^ ((r >> 1) & 3)) << 3)];
    }
    if (t + 2 < nt) { stageA(b2, t + 2); stageB(b2, t + 2); }
    __builtin_amdgcn_s_setprio(1);
#pragma unroll
    for (int mi = 0; mi < MI; mi++)
#pragma unroll
      for (int ni = 0; ni < 4; ni++)
        acc[mi][ni] = __builtin_amdgcn_mfma_f32_16x16x32_bf16(afr[mi], bfr[ni], acc[mi][ni], 0, 0, 0);
    __builtin_amdgcn_s_setprio(0);
    if (t + 1 < nt) {
      // my ds_reads drained before anyone can overwrite buf[cb] (tile t+3 stages, post-barrier)
      asm volatile("s_waitcnt lgkmcnt(0)" ::: "memory");
      if (t + 2 < nt) {
        if constexpr (AW == 2) asm volatile("s_waitcnt vmcnt(4)" ::: "memory");
        else                   asm volatile("s_waitcnt vmcnt(3)" ::: "memory");
      } else {
        asm volatile("s_waitcnt vmcnt(0)" ::: "memory");
      }
      __builtin_amdgcn_s_barrier();
      asm volatile("" ::: "memory");
    }
  }

  const int cm4 = qq * 4;
#pragma unroll
  for (int mi = 0; mi < MI; mi++) {
#pragma unroll
    for (int ni = 0; ni < 4; ni++) {
#pragma unroll
      for (int r = 0; r < 4; r++) {
        const int grow = bm + ra0 + mi * 16 + cm4 + r;
        const int gcol = bn + rb0 + ni * 16 + fr;
        const size_t off = (size_t)grow * N + gcol;
        const float v = acc[mi][ni][r];
        if (EPI == 0) {
          Cb[off] = f2bf(v);
        } else if (EPI == 1) {
          Cf[off] += v;
        } else {
          Cb[off] = f2bf(siluf(bf2f(Cb[off])) * v);
        }
      }
    }
  }
}

// ---------------- ba = h @ ba_w^T ----------------
__global__ __launch_bounds__(256) void ba_gemm_kernel(const float* __restrict__ h_in,
                                                      const float* __restrict__ ba_w,
                                                      float* __restrict__ ba_out) {
  __shared__ __align__(16) float hl[2048];
  __shared__ float red[32][9];
  const int t = blockIdx.x;
  const int tid = threadIdx.x;
  const float4* hr = (const float4*)(h_in + (size_t)t * DMODEL);
  ((float4*)hl)[tid] = hr[tid];
  ((float4*)hl)[tid + 256] = hr[tid + 256];
  __syncthreads();
  const int c = tid & 31;
  const int p = tid >> 5;
  const float* wrow = ba_w + (size_t)c * DMODEL + p * 256;
  const float* hrow = hl + p * 256;
  float s = 0.f;
#pragma unroll 8
  for (int k = 0; k < 256; k++) s += hrow[k] * wrow[k];
  red[c][p] = s;
  __syncthreads();
  if (tid < 32) {
    float tot = 0.f;
#pragma unroll
    for (int q = 0; q < 8; q++) tot += red[tid][q];
    ba_out[(size_t)t * 32 + tid] = tot;
  }
}

// ---------------- extract z columns from bf16 qkvz ----------------
__global__ __launch_bounds__(256) void zcopy_kernel(const unsigned short* __restrict__ qkvz,
                                                    unsigned short* __restrict__ z) {
  const int idx = blockIdx.x * 256 + threadIdx.x;
  const int t = idx >> 8;
  const int c8 = (idx & 255) * 8;
  *(uint4*)(z + (size_t)t * 2048 + c8) =
      *(const uint4*)(qkvz + (size_t)t * CQKVZ + CQKV + c8);
}

// ---------------- causal depthwise conv (K=4) + SiLU; bf16 in, fp32 out ----------------
__global__ __launch_bounds__(256) void conv_silu_kernel(const unsigned short* __restrict__ qkvz,
                                                        const float* __restrict__ conv_w,
                                                        const float* __restrict__ mask,
                                                        float* __restrict__ mixed) {
  const int idx = blockIdx.x * 256 + threadIdx.x;
  const int c4 = (idx % 1536) * 4;
  const int t = idx / 1536;
  const float4 w0 = *(const float4*)(conv_w + (size_t)c4 * 4);
  const float4 w1 = *(const float4*)(conv_w + (size_t)c4 * 4 + 4);
  const float4 w2 = *(const float4*)(conv_w + (size_t)c4 * 4 + 8);
  const float4 w3 = *(const float4*)(conv_w + (size_t)c4 * 4 + 12);
  const float wj0[4] = {w0.x, w0.y, w0.z, w0.w};
  const float wj1[4] = {w1.x, w1.y, w1.z, w1.w};
  const float wj2[4] = {w2.x, w2.y, w2.z, w2.w};
  const float wj3[4] = {w3.x, w3.y, w3.z, w3.w};
  float4 acc = make_float4(0.f, 0.f, 0.f, 0.f);
#pragma unroll
  for (int j = 0; j < 4; j++) {
    const int tt = t - 3 + j;
    if (tt < 0) continue;
    const float m = mask[tt];
    const ushort4 xb = *(const ushort4*)(qkvz + (size_t)tt * CQKVZ + c4);
    acc.x += bf2f(xb.x) * m * wj0[j];
    acc.y += bf2f(xb.y) * m * wj1[j];
    acc.z += bf2f(xb.z) * m * wj2[j];
    acc.w += bf2f(xb.w) * m * wj3[j];
  }
  acc.x = siluf(acc.x); acc.y = siluf(acc.y); acc.z = siluf(acc.z); acc.w = siluf(acc.w);
  *(float4*)(mixed + (size_t)t * CQKV + c4) = acc;
}

// ---------------- l2norm over Dk=128 for q,k heads (in place, fp32) ----------------
__global__ __launch_bounds__(256) void l2norm_kernel(float* __restrict__ mixed) {
  const int r = blockIdx.x * 4 + (threadIdx.x >> 6);
  const int lane = threadIdx.x & 63;
  const int t = r >> 5;
  const int hh = r & 31;
  float* p = mixed + (size_t)t * CQKV + hh * 128 + lane * 2;
  float2 v = *(float2*)p;
  float s = v.x * v.x + v.y * v.y;
#pragma unroll
  for (int off = 32; off > 0; off >>= 1) s += __shfl_down(s, off);
  s = __shfl(s, 0);
  const float rn = rsqrtf(s + 1e-6f);
  v.x *= rn; v.y *= rn;
  *(float2*)p = v;
}

// ---------------- beta, g ----------------
__global__ __launch_bounds__(256) void beta_g_kernel(const float* __restrict__ ba,
                                                     const float* __restrict__ A_log,
                                                     const float* __restrict__ dt_bias,
                                                     const float* __restrict__ mask,
                                                     float* __restrict__ beta,
                                                     float* __restrict__ g) {
  const int idx = blockIdx.x * 256 + threadIdx.x;
  const int t = idx >> 4;
  const int h = idx & 15;
  const float b = ba[(size_t)t * 32 + h];
  const float a = ba[(size_t)t * 32 + 16 + h];
  const float m = mask[t];
  beta[idx] = m / (1.0f + expf(-b));
  const float xx = a + dt_bias[h];
  const float sp = (xx > 20.0f) ? xx : log1pf(expf(xx));
  g[idx] = -expf(A_log[h]) * sp * m;
}

// ---------------- per-chunk cumsum of g + decay factors ----------------
__global__ __launch_bounds__(256) void gcs_kernel(const float* __restrict__ g,
                                                  float* __restrict__ gcsbuf,
                                                  float* __restrict__ edkbuf,
                                                  float* __restrict__ egqbuf,
                                                  float* __restrict__ adecbuf) {
  const int idx = blockIdx.x * 256 + threadIdx.x;  // chunk id = h*64 + n
  if (idx >= 1024) return;
  const int h = idx >> 6;
  const int n = idx & 63;
  const int t0 = n * 64;
  float s = 0.f;
  for (int i = 0; i < 64; i++) {
    s += g[(size_t)(t0 + i) * NH + h];
    gcsbuf[(size_t)idx * 64 + i] = s;
  }
  const float glast = s;
  adecbuf[idx] = __expf(glast);
  for (int i = 0; i < 64; i++) {
    const float gi = gcsbuf[(size_t)idx * 64 + i];
    edkbuf[(size_t)idx * 64 + i] = __expf(glast - gi);
    egqbuf[(size_t)idx * 64 + i] = __expf(gi) * SCALE;
  }
}

// ---------------- per-chunk: A=(k_beta k^T)*decay (strict lower), attn=(q k^T)*decay*scale ----------------
__global__ __launch_bounds__(256) void pre_attn_kernel(const float* __restrict__ mixed,
                                                       const float* __restrict__ gcsbuf,
                                                       const float* __restrict__ betabuf,
                                                       float* __restrict__ abuf,
                                                       float* __restrict__ attnbuf) {
  __shared__ __align__(16) float kl[64][132];
  __shared__ float gcs_s[64];
  __shared__ float betal[64];
  const int blk = blockIdx.x;
  const int h = blk >> 6;
  const int n = blk & 63;
  const int t0 = n * 64;
  const int tid = threadIdx.x;
  if (tid < 64) {
    gcs_s[tid] = gcsbuf[(size_t)blk * 64 + tid];
    betal[tid] = betabuf[(size_t)(t0 + tid) * NH + h];
  }
#pragma unroll
  for (int rep = 0; rep < 8; rep++) {
    const int lin = rep * 256 + tid;
    const int i = lin >> 5;
    const int d = (lin & 31) * 4;
    const float4 kv = *(const float4*)(mixed + (size_t)(t0 + i) * CQKV + 2048 + h * 128 + d);
    *(float4*)&kl[i][d] = kv;
  }
  __syncthreads();
  const int cj = tid & 15;
  const int ri = tid >> 4;
  const int i0 = ri * 4, j0 = cj * 4;
  float accA[4][4], accQ[4][4];
#pragma unroll
  for (int a = 0; a < 4; a++)
#pragma unroll
    for (int b = 0; b < 4; b++) { accA[a][b] = 0.f; accQ[a][b] = 0.f; }
  const float* qbase = mixed + (size_t)t0 * CQKV + h * 128;
#pragma unroll 4
  for (int d = 0; d < 128; d++) {
    const float kj0 = kl[j0][d], kj1 = kl[j0 + 1][d], kj2 = kl[j0 + 2][d], kj3 = kl[j0 + 3][d];
#pragma unroll
    for (int a = 0; a < 4; a++) {
      const float ka = kl[i0 + a][d];
      const float qa = qbase[(size_t)(i0 + a) * CQKV + d];
      accA[a][0] += ka * kj0; accA[a][1] += ka * kj1; accA[a][2] += ka * kj2; accA[a][3] += ka * kj3;
      accQ[a][0] += qa * kj0; accQ[a][1] += qa * kj1; accQ[a][2] += qa * kj2; accQ[a][3] += qa * kj3;
    }
  }
#pragma unroll
  for (int a = 0; a < 4; a++) {
    const int i = i0 + a;
    const float gi = gcs_s[i];
    const float bi = betal[i];
    float4 Av, Qv;
    float dec;
    dec = __expf(fminf(gi - gcs_s[j0 + 0], 0.f));
    Av.x = (i > j0 + 0) ? accA[a][0] * bi * dec : 0.f;
    Qv.x = (i >= j0 + 0) ? accQ[a][0] * dec * SCALE : 0.f;
    dec = __expf(fminf(gi - gcs_s[j0 + 1], 0.f));
    Av.y = (i > j0 + 1) ? accA[a][1] * bi * dec : 0.f;
    Qv.y = (i >= j0 + 1) ? accQ[a][1] * dec * SCALE : 0.f;
    dec = __expf(fminf(gi - gcs_s[j0 + 2], 0.f));
    Av.z = (i > j0 + 2) ? accA[a][2] * bi * dec : 0.f;
    Qv.z = (i >= j0 + 2) ? accQ[a][2] * dec * SCALE : 0.f;
    dec = __expf(fminf(gi - gcs_s[j0 + 3], 0.f));
    Av.w = (i > j0 + 3) ? accA[a][3] * bi * dec : 0.f;
    Qv.w = (i >= j0 + 3) ? accQ[a][3] * dec * SCALE : 0.f;
    *(float4*)(abuf + (size_t)blk * 4096 + i * 64 + j0) = Av;
    *(float4*)(attnbuf + (size_t)blk * 4096 + i * 64 + j0) = Qv;
  }
}

// ---------------- per-chunk: T = (I+A)^-1, then T *= beta[col] ----------------
__global__ __launch_bounds__(256) void pre_solve_kernel(const float* __restrict__ abuf,
                                                        const float* __restrict__ betabuf,
                                                        float* __restrict__ tbuf) {
  __shared__ float Al[64][65];
  __shared__ float Tl[64][65];
  const int blk = blockIdx.x;
  const int h = blk >> 6;
  const int n = blk & 63;
  const int t0 = n * 64;
  const int tid = threadIdx.x;
#pragma unroll
  for (int rep = 0; rep < 4; rep++) {
    const int lin = rep * 256 + tid;
    const int i = lin >> 4;
    const int j = (lin & 15) * 4;
    const float4 av = *(const float4*)(abuf + (size_t)blk * 4096 + i * 64 + j);
    Al[i][j] = av.x; Al[i][j + 1] = av.y; Al[i][j + 2] = av.z; Al[i][j + 3] = av.w;
  }
  __syncthreads();
  if (tid < 64) {
    const int j = tid;
    const float bj = betabuf[(size_t)(t0 + j) * NH + h];
    for (int i = 0; i < 64; i++) {
      float s = (i == j) ? 1.0f : 0.0f;
      for (int l = j; l < i; l++) s -= Al[i][l] * Tl[l][j];
      Tl[i][j] = s;
    }
    for (int i = j; i < 64; i++) Tl[i][j] *= bj;
  }
  __syncthreads();
#pragma unroll
  for (int rep = 0; rep < 4; rep++) {
    const int lin = rep * 256 + tid;
    const int i = lin >> 4;
    const int j = (lin & 15) * 4;
    float4 tv;
    tv.x = Tl[i][j]; tv.y = Tl[i][j + 1]; tv.z = Tl[i][j + 2]; tv.w = Tl[i][j + 3];
    *(float4*)(tbuf + (size_t)blk * 4096 + i * 64 + j) = tv;
  }
}

// ---------------- per-chunk: u = Tb @ v (f32) ; w = Tb @ (k * e^gcs) (bf16) ----------------
__global__ __launch_bounds__(256) void pre_uw_kernel(const float* __restrict__ mixed,
                                                     const float* __restrict__ tbuf,
                                                     const float* __restrict__ gcsbuf,
                                                     float* __restrict__ ubuf,
                                                     unsigned short* __restrict__ wbf) {
  __shared__ __align__(16) float Tl[64][68];
  __shared__ __align__(16) float xl[64][132];
  __shared__ float egcs[64];
  const int blk = blockIdx.x;
  const int h = blk >> 6;
  const int n = blk & 63;
  const int t0 = n * 64;
  const int tid = threadIdx.x;
  if (tid < 64) egcs[tid] = __expf(gcsbuf[(size_t)blk * 64 + tid]);
#pragma unroll
  for (int rep = 0; rep < 4; rep++) {
    const int lin = rep * 256 + tid;
    const int i = lin >> 4;
    const int j = (lin & 15) * 4;
    const float4 tv = *(const float4*)(tbuf + (size_t)blk * 4096 + i * 64 + j);
    *(float4*)&Tl[i][j] = tv;
  }
#pragma unroll
  for (int rep = 0; rep < 8; rep++) {
    const int lin = rep * 256 + tid;
    const int i = lin >> 5;
    const int d = (lin & 31) * 4;
    const float4 vv = *(const float4*)(mixed + (size_t)(t0 + i) * CQKV + 4096 + h * 128 + d);
    *(float4*)&xl[i][d] = vv;
  }
  __syncthreads();
  const int cgu = tid & 15;
  const int riu = tid >> 4;
  const int i0 = riu * 4;
  const int d0 = cgu * 8;
  float acc[4][8];
#pragma unroll
  for (int a = 0; a < 4; a++)
#pragma unroll
    for (int b = 0; b < 8; b++) acc[a][b] = 0.f;
#pragma unroll 2
  for (int j = 0; j < 64; j++) {
    const float tv[4] = {Tl[i0][j], Tl[i0 + 1][j], Tl[i0 + 2][j], Tl[i0 + 3][j]};
    const float4 x0 = *(const float4*)&xl[j][d0];
    const float4 x1 = *(const float4*)&xl[j][d0 + 4];
    const float xv[8] = {x0.x, x0.y, x0.z, x0.w, x1.x, x1.y, x1.z, x1.w};
#pragma unroll
    for (int a = 0; a < 4; a++)
#pragma unroll
      for (int b = 0; b < 8; b++) acc[a][b] += tv[a] * xv[b];
  }
#pragma unroll
  for (int a = 0; a < 4; a++) {
    float* up = ubuf + (size_t)(t0 + i0 + a) * 2048 + h * 128 + d0;
    *(float4*)up = make_float4(acc[a][0], acc[a][1], acc[a][2], acc[a][3]);
    *(float4*)(up + 4) = make_float4(acc[a][4], acc[a][5], acc[a][6], acc[a][7]);
  }
  __syncthreads();
#pragma unroll
  for (int rep = 0; rep < 8; rep++) {
    const int lin = rep * 256 + tid;
    const int i = lin >> 5;
    const int d = (lin & 31) * 4;
    float4 kv = *(const float4*)(mixed + (size_t)(t0 + i) * CQKV + 2048 + h * 128 + d);
    const float e = egcs[i];
    kv.x *= e; kv.y *= e; kv.z *= e; kv.w *= e;
    *(float4*)&xl[i][d] = kv;
  }
  __syncthreads();
#pragma unroll
  for (int a = 0; a < 4; a++)
#pragma unroll
    for (int b = 0; b < 8; b++) acc[a][b] = 0.f;
#pragma unroll 2
  for (int j = 0; j < 64; j++) {
    const float tv[4] = {Tl[i0][j], Tl[i0 + 1][j], Tl[i0 + 2][j], Tl[i0 + 3][j]};
    const float4 x0 = *(const float4*)&xl[j][d0];
    const float4 x1 = *(const float4*)&xl[j][d0 + 4];
    const float xv[8] = {x0.x, x0.y, x0.z, x0.w, x1.x, x1.y, x1.z, x1.w};
#pragma unroll
    for (int a = 0; a < 4; a++)
#pragma unroll
      for (int b = 0; b < 8; b++) acc[a][b] += tv[a] * xv[b];
  }
#pragma unroll
  for (int a = 0; a < 4; a++) {
    unsigned short* wp = wbf + (size_t)(t0 + i0 + a) * 2048 + h * 128 + d0;
    *(ushort4*)wp = pack4(acc[a][0], acc[a][1], acc[a][2], acc[a][3]);
    *(ushort4*)(wp + 4) = pack4(acc[a][4], acc[a][5], acc[a][6], acc[a][7]);
  }
}

// ---------------- per-chunk: kdT[blk][d][l] = bf16( k[t0+l][d] * edk[blk][l] ) ----------------
__global__ __launch_bounds__(256) void ktrans_kernel(const float* __restrict__ mixed,
                                                     const float* __restrict__ edkbuf,
                                                     unsigned short* __restrict__ kdT) {
  __shared__ __align__(16) float kl[64][132];
  __shared__ float edk_s[64];
  const int blk = blockIdx.x;
  const int h = blk >> 6;
  const int n = blk & 63;
  const int t0 = n * 64;
  const int tid = threadIdx.x;
  if (tid < 64) edk_s[tid] = edkbuf[(size_t)blk * 64 + tid];
#pragma unroll
  for (int q = 0; q < 8; q++) {
    const int idx = tid + q * 256;
    const int l = idx >> 5, c4 = (idx & 31) * 4;
    *(float4*)&kl[l][c4] = *(const float4*)(mixed + (size_t)(t0 + l) * CQKV + 2048 + h * 128 + c4);
  }
  __syncthreads();
#pragma unroll
  for (int q = 0; q < 4; q++) {
    const int idx = tid + q * 256;
    const int d = idx >> 3, l8 = (idx & 7) * 8;
    float v[8];
#pragma unroll
    for (int j = 0; j < 8; j++) v[j] = kl[l8 + j][d] * edk_s[l8 + j];
    unsigned short* p = kdT + (size_t)blk * 8192 + d * 64 + l8;
    *(ushort4*)p = pack4(v[0], v[1], v[2], v[3]);
    *(ushort4*)(p + 4) = pack4(v[4], v[5], v[6], v[7]);
  }
}

// ---------------- MFMA sequential scan: 1 block = 1 head, 8 waves, S^T held in accumulators ----------------
__global__ __launch_bounds__(512) void scan_kernel(const unsigned short* __restrict__ wbf,
                                                   const unsigned short* __restrict__ kdT,
                                                   const float* __restrict__ ubuf,
                                                   const float* __restrict__ adecbuf,
                                                   unsigned short* __restrict__ STb,
                                                   unsigned short* __restrict__ vtb) {
  __shared__ __align__(16) unsigned short w_lds[64 * 128];   // [l][d] bf16, xor-swizzled
  __shared__ __align__(16) unsigned short kT_lds[128 * 64];  // [d][l] bf16, xor-swizzled
  __shared__ __align__(16) unsigned short st_lds[128 * 128]; // [c][d] bf16, xor-swizzled
  __shared__ __align__(16) unsigned short vt_lds[128 * 64];  // [c][l] bf16, xor-swizzled
  __shared__ __align__(16) float u_lds[64 * 132];            // [l][c] f32 (pad 132)
  const int h = blockIdx.x;
  const int tid = threadIdx.x;
  const int ln = tid & 63;
  const int wv = tid >> 6;   // 0..7
  const int fr = ln & 15;
  const int g = ln >> 4;     // 0..3
  const int lt = wv & 3;     // phase-B l-tile
  const int ch = wv >> 2;    // phase-B c-half
  const f32x4 zero = {0.f, 0.f, 0.f, 0.f};

  uint4 wreg[2], kreg[2];
  float4 ureg[4];
  // prefetch chunk 0
#pragma unroll
  for (int q = 0; q < 2; q++) {
    const int idx = tid + q * 512;
    const int row = idx >> 4, c8 = (idx & 15) * 8;
    wreg[q] = *(const uint4*)(wbf + (size_t)row * 2048 + h * 128 + c8);
    const int d = idx >> 3, l8 = (idx & 7) * 8;
    kreg[q] = *(const uint4*)(kdT + (size_t)(h * 64) * 8192 + d * 64 + l8);
  }
#pragma unroll
  for (int q = 0; q < 4; q++) {
    const int idx = tid + q * 512;
    const int row = idx >> 5, c4 = (idx & 31) * 4;
    ureg[q] = *(const float4*)(ubuf + (size_t)row * 2048 + h * 128 + c4);
  }

  f32x4 acc2[8];
#pragma unroll
  for (int ct = 0; ct < 8; ct++) acc2[ct] = zero;

  for (int n = 0; n < 64; n++) {
    const int blk = h * 64 + n;
    // ---- step 1: stage w,u for chunk n; dump S_n^T -> st_lds ----
#pragma unroll
    for (int q = 0; q < 2; q++) {
      const int idx = tid + q * 512;
      const int row = idx >> 4, c8 = (idx & 15) * 8;
      *(uint4*)&w_lds[row * 128 + (((c8 >> 3) ^ (row & 7)) << 3)] = wreg[q];
    }
#pragma unroll
    for (int q = 0; q < 4; q++) {
      const int idx = tid + q * 512;
      const int row = idx >> 5, c4 = (idx & 31) * 4;
      *(float4*)&u_lds[row * 132 + c4] = ureg[q];
    }
    {
      const int db = wv * 16 + g * 4;
#pragma unroll
      for (int ct = 0; ct < 8; ct++) {
        const int c = ct * 16 + fr;
        *(ushort4*)&st_lds[c * 128 + (((db >> 3) ^ (c & 7)) << 3) + (db & 7)] =
            pack4(acc2[ct][0], acc2[ct][1], acc2[ct][2], acc2[ct][3]);
      }
    }
    __syncthreads();  // (A)
    // ---- step 2: stage kT; prefetch n+1; export S_n; v_new = u - w@S ----
#pragma unroll
    for (int q = 0; q < 2; q++) {
      const int idx = tid + q * 512;
      const int d = idx >> 3, l8 = (idx & 7) * 8;
      *(uint4*)&kT_lds[d * 64 + (((l8 >> 3) ^ (d & 7)) << 3)] = kreg[q];
    }
    if (n < 63) {
      const int t0n = (n + 1) * 64;
#pragma unroll
      for (int q = 0; q < 2; q++) {
        const int idx = tid + q * 512;
        const int row = idx >> 4, c8 = (idx & 15) * 8;
        wreg[q] = *(const uint4*)(wbf + (size_t)(t0n + row) * 2048 + h * 128 + c8);
        const int d = idx >> 3, l8 = (idx & 7) * 8;
        kreg[q] = *(const uint4*)(kdT + (size_t)(blk + 1) * 8192 + d * 64 + l8);
      }
#pragma unroll
      for (int q = 0; q < 4; q++) {
        const int idx = tid + q * 512;
        const int row = idx >> 5, c4 = (idx & 31) * 4;
        ureg[q] = *(const float4*)(ubuf + (size_t)(t0n + row) * 2048 + h * 128 + c4);
      }
    }
#pragma unroll
    for (int q = 0; q < 4; q++) {  // S_n^T -> global (unswizzle)
      const int idx = tid + q * 512;
      const int c = idx >> 4, dg = idx & 15;
      *(uint4*)(STb + (size_t)blk * 16384 + c * 128 + dg * 8) =
          *(const uint4*)&st_lds[c * 128 + ((dg ^ (c & 7)) << 3)];
    }
    f32x4 acc1[4];
#pragma unroll
    for (int ct = 0; ct < 4; ct++) acc1[ct] = zero;
#pragma unroll
    for (int ks = 0; ks < 4; ks++) {
      const int kb = ks * 4 + g;
      const int ar = lt * 16 + fr;
      const bf16x8 a = *(const bf16x8*)&w_lds[ar * 128 + ((kb ^ (ar & 7)) << 3)];
#pragma unroll
      for (int ct = 0; ct < 4; ct++) {
        const int c = (ch * 4 + ct) * 16 + fr;
        const bf16x8 b = *(const bf16x8*)&st_lds[c * 128 + ((kb ^ (c & 7)) << 3)];
        acc1[ct] = __builtin_amdgcn_mfma_f32_16x16x32_bf16(a, b, acc1[ct], 0, 0, 0);
      }
    }
    {
      const int lb = lt * 16 + g * 4;
#pragma unroll
      for (int ct = 0; ct < 4; ct++) {
        const int c = (ch * 4 + ct) * 16 + fr;
        const float v0 = u_lds[(lb + 0) * 132 + c] - acc1[ct][0];
        const float v1 = u_lds[(lb + 1) * 132 + c] - acc1[ct][1];
        const float v2 = u_lds[(lb + 2) * 132 + c] - acc1[ct][2];
        const float v3 = u_lds[(lb + 3) * 132 + c] - acc1[ct][3];
        *(ushort4*)&vt_lds[c * 64 + (((lb >> 3) ^ (c & 7)) << 3) + (lb & 7)] =
            pack4(v0, v1, v2, v3);
      }
    }
    const float adec = adecbuf[blk];
    __syncthreads();  // (B)
    // ---- step 3: export v_new^T; S = a*S + kdec^T @ v_new ----
#pragma unroll
    for (int q = 0; q < 2; q++) {
      const int idx = tid + q * 512;
      const int c = idx >> 3, lg = idx & 7;
      *(uint4*)(vtb + (size_t)blk * 8192 + c * 64 + lg * 8) =
          *(const uint4*)&vt_lds[c * 64 + ((lg ^ (c & 7)) << 3)];
    }
#pragma unroll
    for (int ct = 0; ct < 8; ct++) {
      acc2[ct][0] *= adec; acc2[ct][1] *= adec; acc2[ct][2] *= adec; acc2[ct][3] *= adec;
    }
#pragma unroll
    for (int ks = 0; ks < 2; ks++) {
      const int kb = ks * 4 + g;
      const int ar = wv * 16 + fr;
      const bf16x8 a = *(const bf16x8*)&kT_lds[ar * 64 + ((kb ^ (ar & 7)) << 3)];
#pragma unroll
      for (int ct = 0; ct < 8; ct++) {
        const int c = ct * 16 + fr;
        const bf16x8 b = *(const bf16x8*)&vt_lds[c * 64 + ((kb ^ (c & 7)) << 3)];
        acc2[ct] = __builtin_amdgcn_mfma_f32_16x16x32_bf16(a, b, acc2[ct], 0, 0, 0);
      }
    }
  }
}

// ---------------- MFMA o-compute + fused gated RMSNorm ----------------
__global__ __launch_bounds__(256) void ocomp_kernel(const float* __restrict__ mixed,
                                                    const unsigned short* __restrict__ STbuf,
                                                    const unsigned short* __restrict__ vtbuf,
                                                    const float* __restrict__ attnbuf,
                                                    const float* __restrict__ egqbuf,
                                                    const unsigned short* __restrict__ zb,
                                                    const float* __restrict__ onw,
                                                    unsigned short* __restrict__ ob) {
  __shared__ __align__(16) unsigned short STl[128 * 128];  // [c][d]
  __shared__ __align__(16) unsigned short vtl[128 * 64];   // [c][l]
  __shared__ __align__(16) unsigned short ql[64 * 128];    // [i][d]
  __shared__ __align__(16) unsigned short al[64 * 64];     // [i][l]
  const int blk = blockIdx.x;
  const int h = blk >> 6;
  const int n = blk & 63;
  const int t0 = n * 64;
  const int tid = threadIdx.x;
#pragma unroll
  for (int q = 0; q < 8; q++) {
    const int idx = tid + q * 256;
    const int c = idx >> 4, dg = idx & 15;
    *(uint4*)&STl[c * 128 + ((dg ^ (c & 7)) << 3)] =
        *(const uint4*)(STbuf + (size_t)blk * 16384 + c * 128 + dg * 8);
  }
#pragma unroll
  for (int q = 0; q < 4; q++) {
    const int idx = tid + q * 256;
    const int c = idx >> 3, lg = idx & 7;
    *(uint4*)&vtl[c * 64 + ((lg ^ (c & 7)) << 3)] =
        *(const uint4*)(vtbuf + (size_t)blk * 8192 + c * 64 + lg * 8);
  }
#pragma unroll
  for (int q = 0; q < 8; q++) {
    const int idx = tid + q * 256;
    const int i = idx >> 5, c4 = (idx & 31) * 4;
    const float eg = egqbuf[(size_t)blk * 64 + i];
    const float4 v = *(const float4*)(mixed + (size_t)(t0 + i) * CQKV + h * 128 + c4);
    *(ushort4*)&ql[i * 128 + (((c4 >> 3) ^ (i & 7)) << 3) + (c4 & 7)] =
        pack4(v.x * eg, v.y * eg, v.z * eg, v.w * eg);
  }
#pragma unroll
  for (int q = 0; q < 4; q++) {
    const int idx = tid + q * 256;
    const int i = idx >> 4, l4 = (idx & 15) * 4;
    const float4 v = *(const float4*)(attnbuf + (size_t)blk * 4096 + i * 64 + l4);
    *(ushort4*)&al[i * 64 + (((l4 >> 3) ^ (i & 7)) << 3) + (l4 & 7)] =
        pack4(v.x, v.y, v.z, v.w);
  }
  __syncthreads();
  const int ln = tid & 63;
  const int wv = tid >> 6;
  const int fr = ln & 15;
  const int g = ln >> 4;
  const int i0 = wv * 16;
  f32x4 acc[8];
  const f32x4 zero = {0.f, 0.f, 0.f, 0.f};
#pragma unroll
  for (int nt = 0; nt < 8; nt++) acc[nt] = zero;
#pragma unroll
  for (int ks = 0; ks < 4; ks++) {
    const int kb = ks * 4 + g;
    const int ar = i0 + fr;
    const bf16x8 a = *(const bf16x8*)&ql[ar * 128 + ((kb ^ (ar & 7)) << 3)];
#pragma unroll
    for (int nt = 0; nt < 8; nt++) {
      const int c = nt * 16 + fr;
      const bf16x8 b = *(const bf16x8*)&STl[c * 128 + ((kb ^ (c & 7)) << 3)];
      acc[nt] = __builtin_amdgcn_mfma_f32_16x16x32_bf16(a, b, acc[nt], 0, 0, 0);
    }
  }
#pragma unroll
  for (int ks = 0; ks < 2; ks++) {
    const int kb = ks * 4 + g;
    const int ar = i0 + fr;
    const bf16x8 a = *(const bf16x8*)&al[ar * 64 + ((kb ^ (ar & 7)) << 3)];
#pragma unroll
    for (int nt = 0; nt < 8; nt++) {
      const int c = nt * 16 + fr;
      const bf16x8 b = *(const bf16x8*)&vtl[c * 64 + ((kb ^ (c & 7)) << 3)];
      acc[nt] = __builtin_amdgcn_mfma_f32_16x16x32_bf16(a, b, acc[nt], 0, 0, 0);
    }
  }
  float s0 = 0.f, s1 = 0.f, s2 = 0.f, s3 = 0.f;
#pragma unroll
  for (int nt = 0; nt < 8; nt++) {
    s0 += acc[nt][0] * acc[nt][0];
    s1 += acc[nt][1] * acc[nt][1];
    s2 += acc[nt][2] * acc[nt][2];
    s3 += acc[nt][3] * acc[nt][3];
  }
#pragma unroll
  for (int m = 1; m < 16; m <<= 1) {
    s0 += __shfl_xor(s0, m);
    s1 += __shfl_xor(s1, m);
    s2 += __shfl_xor(s2, m);
    s3 += __shfl_xor(s3, m);
  }
  float rn[4];
  rn[0] = rsqrtf(s0 * (1.0f / 128.0f) + 1e-5f);
  rn[1] = rsqrtf(s1 * (1.0f / 128.0f) + 1e-5f);
  rn[2] = rsqrtf(s2 * (1.0f / 128.0f) + 1e-5f);
  rn[3] = rsqrtf(s3 * (1.0f / 128.0f) + 1e-5f);
#pragma unroll
  for (int nt = 0; nt < 8; nt++) {
    const int c = nt * 16 + fr;
    const float wn = onw[c];
#pragma unroll
    for (int r = 0; r < 4; r++) {
      const size_t off = (size_t)(t0 + i0 + g * 4 + r) * 2048 + h * 128 + c;
      const float zz = siluf(bf2f(zb[off]));
      ob[off] = f2bf(acc[nt][r] * rn[r] * wn * zz);
    }
  }
}

// ---------------- helpers ----------------
__global__ __launch_bounds__(256) void copy_kernel(const float* __restrict__ in,
                                                   float* __restrict__ out) {
  const int i = blockIdx.x * 256 + threadIdx.x;
  ((float4*)out)[i] = ((const float4*)in)[i];
}

extern "C" void kernel_launch(void* const* d_in, const int* in_sizes, int n_in,
                              void* d_out, int out_size, void* d_ws, size_t ws_size,
                              hipStream_t stream) {
  (void)in_sizes; (void)n_in; (void)out_size;
  const float* x        = (const float*)d_in[0];
  const float* mask     = (const float*)d_in[1];
  const float* ln1_w    = (const float*)d_in[2];
  const float* qkvz_w   = (const float*)d_in[3];
  const float* ba_w     = (const float*)d_in[4];
  const float* conv_w   = (const float*)d_in[5];
  const float* A_log    = (const float*)d_in[6];
  const float* dt_bias  = (const float*)d_in[7];
  const float* o_norm_w = (const float*)d_in[8];
  const float* out_w    = (const float*)d_in[9];
  const float* ln2_w    = (const float*)d_in[10];
  const float* gate_w   = (const float*)d_in[11];
  const float* up_w     = (const float*)d_in[12];
  const float* down_w   = (const float*)d_in[13];
  float* out = (float*)d_out;

  const size_t NEED_BYTES = (size_t)75825152 * 4;
  if (ws_size < NEED_BYTES) return;

  float* ws = (float*)d_ws;
  float* mixed_buf = ws;
  unsigned short* Wg = (unsigned short*)ws;
  unsigned short* Wu = (unsigned short*)(ws + 8388608);
  unsigned short* Wd = (unsigned short*)(ws + 16777216);
  unsigned short* qkvz_bf = (unsigned short*)(ws + 25165824);
  float* u_buf = ws + 25165824;
  unsigned short* wbf = (unsigned short*)(ws + 33554432);
  unsigned short* kdT = (unsigned short*)(ws + 37748736);
  unsigned short* gate_bf = (unsigned short*)(ws + 25165824);
  unsigned short* z_bf = (unsigned short*)(ws + 41943040);
  float* h_buf = ws + 46137344;
  float* a_buf = ws + 46137344;
  unsigned short* vt_buf = (unsigned short*)(ws + 46137344);
  float* t_buf = ws + 50331648;
  unsigned short* h_bf  = (unsigned short*)(ws + 54525952);
  unsigned short* ob    = (unsigned short*)(ws + 54525952);
  unsigned short* h2_bf = (unsigned short*)(ws + 54525952);
  float* attn_buf = ws + 58720256;
  unsigned short* Wq = (unsigned short*)(ws + 62914560);
  unsigned short* ST_buf = (unsigned short*)(ws + 62914560);
  unsigned short* Wo = (unsigned short*)(ws + 71303168);
  float* ba_buf   = ws + 73400320;
  float* beta_buf = ws + 73531392;
  float* g_buf    = ws + 73596928;
  float* gcs_buf  = ws + 73662464;
  float* edk_buf  = ws + 73728000;
  float* egq_buf  = ws + 73793536;
  float* adec_buf = ws + 73859072;

  rmsnorm_kernel<1><<<4096, 256, 0, stream>>>(x, ln1_w, h_buf, h_bf);
  f2b_kernel<<<8192, 256, 0, stream>>>(qkvz_w, Wq);
  gemm256_kernel<0, 256><<<512, 512, 0, stream>>>(h_bf, Wq, nullptr, qkvz_bf, 4096, 8192, 2048);
  ba_gemm_kernel<<<4096, 256, 0, stream>>>(h_buf, ba_w, ba_buf);
  zcopy_kernel<<<4096, 256, 0, stream>>>(qkvz_bf, z_bf);
  conv_silu_kernel<<<24576, 256, 0, stream>>>(qkvz_bf, conv_w, mask, mixed_buf);
  l2norm_kernel<<<32768, 256, 0, stream>>>(mixed_buf);
  beta_g_kernel<<<256, 256, 0, stream>>>(ba_buf, A_log, dt_bias, mask, beta_buf, g_buf);
  gcs_kernel<<<4, 256, 0, stream>>>(g_buf, gcs_buf, edk_buf, egq_buf, adec_buf);
  pre_attn_kernel<<<1024, 256, 0, stream>>>(mixed_buf, gcs_buf, beta_buf, a_buf, attn_buf);
  pre_solve_kernel<<<1024, 256, 0, stream>>>(a_buf, beta_buf, t_buf);
  pre_uw_kernel<<<1024, 256, 0, stream>>>(mixed_buf, t_buf, gcs_buf, u_buf, wbf);
  ktrans_kernel<<<1024, 256, 0, stream>>>(mixed_buf, edk_buf, kdT);
  scan_kernel<<<16, 512, 0, stream>>>(wbf, kdT, u_buf, adec_buf, ST_buf, vt_buf);
  ocomp_kernel<<<1024, 256, 0, stream>>>(mixed_buf, ST_buf, vt_buf, attn_buf, egq_buf,
                                         z_bf, o_norm_w, ob);
  f2b_kernel<<<8192, 256, 0, stream>>>(gate_w, Wg);
  f2b_kernel<<<8192, 256, 0, stream>>>(up_w, Wu);
  f2b_kernel<<<8192, 256, 0, stream>>>(down_w, Wd);
  f2b_kernel<<<2048, 256, 0, stream>>>(out_w, Wo);
  copy_kernel<<<8192, 256, 0, stream>>>(x, out);
  gemm256_kernel<1, 128><<<256, 512, 0, stream>>>(ob, Wo, out, nullptr, 4096, 2048, 2048);
  rmsnorm_kernel<2><<<4096, 256, 0, stream>>>(out, ln2_w, nullptr, h2_bf);
  gemm256_kernel<0, 256><<<512, 512, 0, stream>>>(h2_bf, Wg, nullptr, gate_bf, 4096, 8192, 2048);
  gemm256_kernel<2, 256><<<512, 512, 0, stream>>>(h2_bf, Wu, nullptr, gate_bf, 4096, 8192, 2048);
  gemm256_kernel<1, 128><<<256, 512, 0, stream>>>(gate_bf, Wd, out, nullptr, 4096, 2048, 8192);
}